// Round 1
// baseline (226.111 us; speedup 1.0000x reference)
//
#include <hip/hip_runtime.h>
#include <stdint.h>

// ---------------------------------------------------------------------------
// SingleHeadedAttention (Mega-style, laplacian attn fn, causal, T5 rel bias)
// B=4, S=2048, DIM=1024, DQK=128, DV=1024.  fp32 in/out, bf16 MFMA internals.
// R8: R7 with the k_gemm_out grid bug fixed (grid.y 32 -> 64; bt=y>>4 needs
//     y in 0..63 for 4 batches — batches 2,3 were never computed in R7).
// R9: byte-identical resubmission of R8 — previous round's bench was an
//     MI355X container failure (no measurement, no counters). Re-establishing
//     baseline + rocprof before any further edits.
//   TILED: element (row,k) of [R][K] at
//     ((row>>4)*(K>>5) + (k>>5))*512 + ((k>>3)&3)*128 + (row&15)*8 + (k&7).
//   Lane l's MFMA fragment of a 16x32 block = 16 contiguous bytes at
//   base + l*16 -> one coalesced global_load_dwordx4 per fragment. No LDS,
//   no barriers, no DMA in the GEMMs; register double-buffer (2 k-blocks);
//   4 independent 64x64 waves per 256-thread block (128x128 block tile).
// ---------------------------------------------------------------------------

#define B_   4
#define S_   2048
#define DIM_ 1024
#define DQK  128
#define DV   1024
#define NQV  1152

typedef __attribute__((ext_vector_type(8))) short short8;   // 8 bf16
typedef __attribute__((ext_vector_type(4))) float f32x4;    // MFMA C/D

__device__ __forceinline__ uint16_t f32_to_bf16(float f) {
  uint32_t u = __float_as_uint(f);
  u += 0x7FFFu + ((u >> 16) & 1u);          // round-to-nearest-even
  return (uint16_t)(u >> 16);
}

__device__ __forceinline__ float silu_f(float x) {
  return x / (1.0f + expf(-x));
}

__device__ __forceinline__ float laplacian_attn(float x) {
  return 0.5f * (1.0f + erff((x - 0.70710678118654752f) * 0.79788456080286536f));
}

// ---- wave-private 64x64 GEMM on TILED operands, register pipeline ---------
// A tiled [RA][K] row-blocks rbA..+3, Bt tiled [RB][K] row-blocks rbB..+3.
// KBa/KBb = K>>5. nkb even, >=2. Fragments global->VGPR, contiguous 16B/lane.
__device__ __forceinline__ void wave_gemm_r(
    const uint16_t* __restrict__ A, int KBa, int rbA,
    const uint16_t* __restrict__ Bt, int KBb, int rbB,
    int nkb, f32x4 acc[4][4])
{
  const int lane = threadIdx.x & 63;

  const uint16_t* pa[4];
  const uint16_t* pb[4];
  #pragma unroll
  for (int mt = 0; mt < 4; mt++)
    pa[mt] = A + (size_t)(rbA + mt) * KBa * 512 + lane * 8;
  #pragma unroll
  for (int nt = 0; nt < 4; nt++)
    pb[nt] = Bt + (size_t)(rbB + nt) * KBb * 512 + lane * 8;

  #pragma unroll
  for (int mt = 0; mt < 4; mt++)
    #pragma unroll
    for (int nt = 0; nt < 4; nt++) {
      f32x4 z = {0.0f, 0.0f, 0.0f, 0.0f};
      acc[mt][nt] = z;
    }

  short8 fa0[4], fb0[4], fa1[4], fb1[4];

  auto loads = [&](short8 fa[4], short8 fb[4], int kb) {
    #pragma unroll
    for (int mt = 0; mt < 4; mt++)
      fa[mt] = *(const short8*)(pa[mt] + (size_t)kb * 512);
    #pragma unroll
    for (int nt = 0; nt < 4; nt++)
      fb[nt] = *(const short8*)(pb[nt] + (size_t)kb * 512);
  };
  auto mfmas = [&](short8 fa[4], short8 fb[4]) {
    #pragma unroll
    for (int mt = 0; mt < 4; mt++)
      #pragma unroll
      for (int nt = 0; nt < 4; nt++)
        acc[mt][nt] = __builtin_amdgcn_mfma_f32_16x16x32_bf16(
            fa[mt], fb[nt], acc[mt][nt], 0, 0, 0);
  };

  loads(fa0, fb0, 0);
  loads(fa1, fb1, 1);
  for (int kb = 2; kb < nkb; kb += 2) {
    mfmas(fa0, fb0);
    loads(fa0, fb0, kb);
    mfmas(fa1, fb1);
    loads(fa1, fb1, kb + 1);
  }
  mfmas(fa0, fb0);
  mfmas(fa1, fb1);
}

// 256-thread block = 4 independent waves over a 128x128 tile.
// wave w: rows +(w>>1)*64 (row-blocks +(w>>1)*4), cols +(w&1)*64.
#define WAVE_PREAMBLE                                  \
  int lane = threadIdx.x & 63;                         \
  int wave = threadIdx.x >> 6;                         \
  int lane16 = lane & 15;                              \
  int quad = lane >> 4;                                \
  int wrow = (wave >> 1) * 64;                         \
  int wcol = (wave & 1) * 64;

// ---- prep kernels ----------------------------------------------------------

// x fp32 [8192][1024] -> xb TILED bf16 (output linear/coalesced).
__global__ __launch_bounds__(256) void k_prep_x(
    const float* __restrict__ x, uint16_t* __restrict__ xb)
{
  int t = blockIdx.x * 256 + threadIdx.x;      // 0 .. 8192*128-1
  int i16 = t & 15, oct = (t >> 4) & 3, kb = (t >> 6) & 31, ib = t >> 11;
  const float* src = x + (size_t)(ib * 16 + i16) * DIM_ + kb * 32 + oct * 8;
  float4 a = *(const float4*)src;
  float4 b = *(const float4*)(src + 4);
  short8 o;
  o[0] = f32_to_bf16(a.x); o[1] = f32_to_bf16(a.y);
  o[2] = f32_to_bf16(a.z); o[3] = f32_to_bf16(a.w);
  o[4] = f32_to_bf16(b.x); o[5] = f32_to_bf16(b.y);
  o[6] = f32_to_bf16(b.z); o[7] = f32_to_bf16(b.w);
  *(short8*)(xb + (size_t)t * 8) = o;
}

// wqk [1024][128], wv [1024][1024] fp32 -> wT TILED bf16, rows n=0..1151
__global__ __launch_bounds__(256) void k_prep_w(
    const float* __restrict__ wqk, const float* __restrict__ wv,
    uint16_t* __restrict__ wT)
{
  int t = blockIdx.x * 256 + threadIdx.x;      // 0 .. 1152*128-1
  int n16 = t & 15, oct = (t >> 4) & 3, kb = (t >> 6) & 31, nb = t >> 11;
  int n = nb * 16 + n16;
  int k0 = kb * 32 + oct * 8;
  short8 o;
  if (n < DQK) {
    #pragma unroll
    for (int j = 0; j < 8; j++)
      o[j] = f32_to_bf16(wqk[(size_t)(k0 + j) * DQK + n]);
  } else {
    int nn = n - DQK;
    #pragma unroll
    for (int j = 0; j < 8; j++)
      o[j] = f32_to_bf16(wv[(size_t)(k0 + j) * DV + nn]);
  }
  *(short8*)(wT + (size_t)t * 8) = o;
}

// bias_n[n] = rel_bias[bucket(n)] * sqrt(DQK)
__global__ __launch_bounds__(256) void k_bias(
    const float* __restrict__ rel, float* __restrict__ bias_n)
{
  int n = blockIdx.x * blockDim.x + threadIdx.x;
  if (n >= S_) return;
  int bucket;
  if (n < 16) {
    bucket = n;
  } else {
    float tt = logf((float)n * 0.0625f) / 2.0794415416798357f * 16.0f;
    int vl = 16 + (int)tt;
    bucket = vl < 31 ? vl : 31;
  }
  bias_n[n] = rel[bucket] * 11.313708498984761f;
}

// ---- GEMM kernels ----------------------------------------------------------

// fused projections. grid (9, 64). bx==0 -> q/k epilogue; bx>=1 -> v -> vT.
__global__ __launch_bounds__(256, 3) void k_gemm_qkv(
    const uint16_t* __restrict__ xb, const uint16_t* __restrict__ wT,
    const float* __restrict__ bqk, const float* __restrict__ gamma,
    const float* __restrict__ beta, const float* __restrict__ bv,
    uint16_t* __restrict__ qb, uint16_t* __restrict__ kb,
    uint16_t* __restrict__ vT)
{
  int bx = blockIdx.x, by = blockIdx.y;
  WAVE_PREAMBLE
  f32x4 acc[4][4];
  wave_gemm_r(xb, DIM_ >> 5, by * 8 + (wave >> 1) * 4,
              wT, DIM_ >> 5, bx * 8 + (wave & 1) * 4,
              DIM_ >> 5, acc);

  if (bx == 0) {
    #pragma unroll
    for (int nt = 0; nt < 4; nt++) {
      int col = wcol + nt * 16 + lane16;           // 0..127
      float bb = bqk[col];
      float g0 = gamma[col], b0 = beta[col];
      float g1 = gamma[DQK + col], b1 = beta[DQK + col];
      int coff = (col >> 5) * 512 + ((col >> 3) & 3) * 128 + (col & 7);
      #pragma unroll
      for (int mt = 0; mt < 4; mt++) {
        int rb = by * 8 + (wave >> 1) * 4 + mt;    // row-block, KB=4
        size_t base = (size_t)rb * 4 * 512 + coff + (size_t)(quad * 4) * 8;
        #pragma unroll
        for (int r = 0; r < 4; r++) {
          float s = silu_f(acc[mt][nt][r] + bb);
          qb[base + r * 8] = f32_to_bf16(s * g0 + b0);
          kb[base + r * 8] = f32_to_bf16(s * g1 + b1);
        }
      }
    }
  } else {
    int b = by >> 4;                               // batch (by*128 / 2048)
    uint16_t* vt = vT + (size_t)b * DV * S_;
    #pragma unroll
    for (int nt = 0; nt < 4; nt++) {
      int n = (bx - 1) * 128 + wcol + nt * 16 + lane16;   // 0..1023
      float bb = bv[n];
      #pragma unroll
      for (int mt = 0; mt < 4; mt++) {
        int j0l = (by & 15) * 128 + wrow + mt * 16 + quad * 4; // local seq
        uint16_t v0 = f32_to_bf16(silu_f(acc[mt][nt][0] + bb));
        uint16_t v1 = f32_to_bf16(silu_f(acc[mt][nt][1] + bb));
        uint16_t v2 = f32_to_bf16(silu_f(acc[mt][nt][2] + bb));
        uint16_t v3 = f32_to_bf16(silu_f(acc[mt][nt][3] + bb));
        size_t off = (size_t)((n >> 4) * 64 + (j0l >> 5)) * 512 +
                     ((j0l >> 3) & 3) * 128 + (n & 15) * 8 + (j0l & 7);
        uint2 pk;
        pk.x = (uint32_t)v0 | ((uint32_t)v1 << 16);
        pk.y = (uint32_t)v2 | ((uint32_t)v3 << 16);
        *(uint2*)(vt + off) = pk;
      }
    }
  }
}

// attn = laplacian(q@k^T/S + bias[i-j]) causal, TILED bf16 per batch.
// grid (16, 16, 4): jt, it, b; jt>it skipped (tiles never read downstream).
__global__ __launch_bounds__(256, 3) void k_gemm_sim(
    const uint16_t* __restrict__ qb, const uint16_t* __restrict__ kb,
    const float* __restrict__ bias_n, uint16_t* __restrict__ attn)
{
  int jt = blockIdx.x, it = blockIdx.y, bt = blockIdx.z;
  if (jt > it) return;
  WAVE_PREAMBLE
  f32x4 acc[4][4];
  wave_gemm_r(qb, 4, bt * 128 + it * 8 + (wave >> 1) * 4,
              kb, 4, bt * 128 + jt * 8 + (wave & 1) * 4,
              4, acc);
  uint16_t* ab = attn + (size_t)bt * S_ * S_;
  #pragma unroll
  for (int nt = 0; nt < 4; nt++) {
    int j = jt * 128 + wcol + nt * 16 + lane16;
    size_t joff = (size_t)(j >> 5) * 512 + ((j >> 3) & 3) * 128 + (j & 7);
    #pragma unroll
    for (int mt = 0; mt < 4; mt++) {
      #pragma unroll
      for (int r = 0; r < 4; r++) {
        int i = it * 128 + wrow + mt * 16 + quad * 4 + r;
        float aval = 0.0f;
        if (j <= i) {
          float sim = acc[mt][nt][r] * (1.0f / 2048.0f) + bias_n[i - j];
          aval = laplacian_attn(sim);
        }
        ab[(size_t)(i >> 4) * 64 * 512 + joff + (size_t)(i & 15) * 8] =
            f32_to_bf16(aval);
      }
    }
  }
}

// out = attn @ v, fp32 out. grid (8, 64): y = bt*16 + tt, it balanced so
// co-resident groups get ~constant K; nkb = 4*it+4 (causal bound).
__global__ __launch_bounds__(256, 3) void k_gemm_out(
    const uint16_t* __restrict__ attn, const uint16_t* __restrict__ vT,
    float* __restrict__ out)
{
  int nx = blockIdx.x;
  int y = blockIdx.y;
  int bt = y >> 4, tt = y & 15;
  int it = (bt & 1) ? (15 - tt) : tt;
  int nkb = 4 * it + 4;
  WAVE_PREAMBLE
  f32x4 acc[4][4];
  wave_gemm_r(attn + (size_t)bt * S_ * S_, 64, it * 8 + (wave >> 1) * 4,
              vT + (size_t)bt * DV * S_, 64, nx * 8 + (wave & 1) * 4,
              nkb, acc);
  #pragma unroll
  for (int mt = 0; mt < 4; mt++)
    #pragma unroll
    for (int nt = 0; nt < 4; nt++)
      #pragma unroll
      for (int r = 0; r < 4; r++) {
        int i = it * 128 + wrow + mt * 16 + quad * 4 + r;
        int n = nx * 128 + wcol + nt * 16 + lane16;
        out[((size_t)bt * S_ + i) * DV + n] = acc[mt][nt][r];
      }
}

// ---------------------------------------------------------------------------

extern "C" void kernel_launch(void* const* d_in, const int* in_sizes, int n_in,
                              void* d_out, int out_size, void* d_ws, size_t ws_size,
                              hipStream_t stream)
{
  const float* x     = (const float*)d_in[0];
  const float* wqk   = (const float*)d_in[1];
  const float* bqk   = (const float*)d_in[2];
  const float* gamma = (const float*)d_in[3];
  const float* beta  = (const float*)d_in[4];
  const float* wv    = (const float*)d_in[5];
  const float* bv    = (const float*)d_in[6];
  const float* rel   = (const float*)d_in[7];
  float* out = (float*)d_out;

  char* ws = (char*)d_ws;
  size_t off = 0;
  uint16_t* xb     = (uint16_t*)(ws + off); off += (size_t)B_ * S_ * DIM_ * 2;  // 16 MB
  uint16_t* wT     = (uint16_t*)(ws + off); off += (size_t)NQV * DIM_ * 2;      // 2.25 MB
  uint16_t* qb     = (uint16_t*)(ws + off); off += (size_t)B_ * S_ * DQK * 2;   // 2 MB
  uint16_t* kb     = (uint16_t*)(ws + off); off += (size_t)B_ * S_ * DQK * 2;   // 2 MB
  uint16_t* vT     = (uint16_t*)(ws + off); off += (size_t)B_ * DV * S_ * 2;    // 16 MB
  uint16_t* attn   = (uint16_t*)(ws + off); off += (size_t)B_ * S_ * S_ * 2;    // 32 MB
  float*    bias_n = (float*)(ws + off);    off += (size_t)S_ * 4;              // 8 KB

  k_prep_x<<<dim3(B_ * S_ * DIM_ / 8 / 256), dim3(256), 0, stream>>>(x, xb);
  k_prep_w<<<dim3(NQV * DIM_ / 8 / 256), dim3(256), 0, stream>>>(wqk, wv, wT);
  k_bias<<<dim3(S_ / 256), dim3(256), 0, stream>>>(rel, bias_n);

  k_gemm_qkv<<<dim3(NQV / 128, B_ * S_ / 128), dim3(256), 0, stream>>>(
      xb, wT, bqk, gamma, beta, bv, qb, kb, vT);
  k_gemm_sim<<<dim3(S_ / 128, S_ / 128, B_), dim3(256), 0, stream>>>(
      qb, kb, bias_n, attn);
  k_gemm_out<<<dim3(DV / 128, B_ * S_ / 128), dim3(256), 0, stream>>>(
      attn, vT, out);
}

// Round 2
// 206.673 us; speedup vs baseline: 1.0941x; 1.0941x over previous
//
#include <hip/hip_runtime.h>
#include <stdint.h>

// ---------------------------------------------------------------------------
// SingleHeadedAttention (Mega-style, laplacian attn fn, causal, T5 rel bias)
// B=4, S=2048, DIM=1024, DQK=128, DV=1024.  fp32 in/out, bf16 MFMA internals.
// R10: sim was 46.5us at 1.7% MfmaUtil / 21% VALUBusy -> VALU+latency bound on
//   ocml erff (branchy, ~70 instr) and 64 scattered 2B stores per thread.
//   - fast branchless erf (AS 7.1.26, |eps|<=1.5e-7) w/ v_rcp + native exp
//   - SWAPPED mfma in sim (A=K, B=Q): C-layout then has i=lane16 and four
//     CONSECUTIVE j per quad -> pack 4 bf16 -> one 8B coalesced store.
//   - same swap for q/k projection epilogue (bx==0) in k_gemm_qkv; silu via
//     native __expf + v_rcp.
//   TILED: element (row,k) of [R][K] at
//     ((row>>4)*(K>>5) + (k>>5))*512 + ((k>>3)&3)*128 + (row&15)*8 + (k&7).
//   Lane l's MFMA fragment of a 16x32 block = 16 contiguous bytes at
//   base + l*16 -> one coalesced global_load_dwordx4 per fragment. No LDS,
//   no barriers, no DMA in the GEMMs; register double-buffer (2 k-blocks);
//   4 independent 64x64 waves per 256-thread block (128x128 block tile).
// ---------------------------------------------------------------------------

#define B_   4
#define S_   2048
#define DIM_ 1024
#define DQK  128
#define DV   1024
#define NQV  1152

typedef __attribute__((ext_vector_type(8))) short short8;   // 8 bf16
typedef __attribute__((ext_vector_type(4))) float f32x4;    // MFMA C/D

__device__ __forceinline__ uint16_t f32_to_bf16(float f) {
  uint32_t u = __float_as_uint(f);
  u += 0x7FFFu + ((u >> 16) & 1u);          // round-to-nearest-even
  return (uint16_t)(u >> 16);
}

__device__ __forceinline__ uint32_t pack_bf16(float a, float b) {
  return (uint32_t)f32_to_bf16(a) | ((uint32_t)f32_to_bf16(b) << 16);
}

__device__ __forceinline__ float silu_f(float x) {
  // x * sigmoid(x), native exp + v_rcp (bf16 output tolerates ~1e-6 rel err)
  return x * __builtin_amdgcn_rcpf(1.0f + __expf(-x));
}

// 0.5*(1+erf((x-mu)/(std*sqrt2))), mu=sqrt(0.5), std=sqrt(pi/4).
// Branchless Abramowitz-Stegun 7.1.26 erf approx, |eps| <= 1.5e-7.
__device__ __forceinline__ float laplacian_attn(float x) {
  float z  = (x - 0.70710678118654752f) * 0.79788456080286536f;
  float az = fabsf(z);
  float t  = __builtin_amdgcn_rcpf(fmaf(0.3275911f, az, 1.0f));
  float w  = fmaf(1.061405429f, t, -1.453152027f);
  w = fmaf(w, t, 1.421413741f);
  w = fmaf(w, t, -0.284496736f);
  w = fmaf(w, t, 0.254829592f);
  float P  = w * t;
  float E  = __expf(-z * z);
  float ea = fmaf(-P, E, 1.0f);            // erf(|z|)
  float er = copysignf(ea, z);
  return fmaf(0.5f, er, 0.5f);
}

// ---- wave-private 64x64 GEMM on TILED operands, register pipeline ---------
// A tiled [RA][K] row-blocks rbA..+3, Bt tiled [RB][K] row-blocks rbB..+3.
// KBa/KBb = K>>5. nkb even, >=2. Fragments global->VGPR, contiguous 16B/lane.
__device__ __forceinline__ void wave_gemm_r(
    const uint16_t* __restrict__ A, int KBa, int rbA,
    const uint16_t* __restrict__ Bt, int KBb, int rbB,
    int nkb, f32x4 acc[4][4])
{
  const int lane = threadIdx.x & 63;

  const uint16_t* pa[4];
  const uint16_t* pb[4];
  #pragma unroll
  for (int mt = 0; mt < 4; mt++)
    pa[mt] = A + (size_t)(rbA + mt) * KBa * 512 + lane * 8;
  #pragma unroll
  for (int nt = 0; nt < 4; nt++)
    pb[nt] = Bt + (size_t)(rbB + nt) * KBb * 512 + lane * 8;

  #pragma unroll
  for (int mt = 0; mt < 4; mt++)
    #pragma unroll
    for (int nt = 0; nt < 4; nt++) {
      f32x4 z = {0.0f, 0.0f, 0.0f, 0.0f};
      acc[mt][nt] = z;
    }

  short8 fa0[4], fb0[4], fa1[4], fb1[4];

  auto loads = [&](short8 fa[4], short8 fb[4], int kb) {
    #pragma unroll
    for (int mt = 0; mt < 4; mt++)
      fa[mt] = *(const short8*)(pa[mt] + (size_t)kb * 512);
    #pragma unroll
    for (int nt = 0; nt < 4; nt++)
      fb[nt] = *(const short8*)(pb[nt] + (size_t)kb * 512);
  };
  auto mfmas = [&](short8 fa[4], short8 fb[4]) {
    #pragma unroll
    for (int mt = 0; mt < 4; mt++)
      #pragma unroll
      for (int nt = 0; nt < 4; nt++)
        acc[mt][nt] = __builtin_amdgcn_mfma_f32_16x16x32_bf16(
            fa[mt], fb[nt], acc[mt][nt], 0, 0, 0);
  };

  loads(fa0, fb0, 0);
  loads(fa1, fb1, 1);
  for (int kb = 2; kb < nkb; kb += 2) {
    mfmas(fa0, fb0);
    loads(fa0, fb0, kb);
    mfmas(fa1, fb1);
    loads(fa1, fb1, kb + 1);
  }
  mfmas(fa0, fb0);
  mfmas(fa1, fb1);
}

// 256-thread block = 4 independent waves over a 128x128 tile.
// wave w: rows +(w>>1)*64 (row-blocks +(w>>1)*4), cols +(w&1)*64.
#define WAVE_PREAMBLE                                  \
  int lane = threadIdx.x & 63;                         \
  int wave = threadIdx.x >> 6;                         \
  int lane16 = lane & 15;                              \
  int quad = lane >> 4;                                \
  int wrow = (wave >> 1) * 64;                         \
  int wcol = (wave & 1) * 64;

// ---- prep kernels ----------------------------------------------------------

// x fp32 [8192][1024] -> xb TILED bf16 (output linear/coalesced).
__global__ __launch_bounds__(256) void k_prep_x(
    const float* __restrict__ x, uint16_t* __restrict__ xb)
{
  int t = blockIdx.x * 256 + threadIdx.x;      // 0 .. 8192*128-1
  int i16 = t & 15, oct = (t >> 4) & 3, kb = (t >> 6) & 31, ib = t >> 11;
  const float* src = x + (size_t)(ib * 16 + i16) * DIM_ + kb * 32 + oct * 8;
  float4 a = *(const float4*)src;
  float4 b = *(const float4*)(src + 4);
  short8 o;
  o[0] = f32_to_bf16(a.x); o[1] = f32_to_bf16(a.y);
  o[2] = f32_to_bf16(a.z); o[3] = f32_to_bf16(a.w);
  o[4] = f32_to_bf16(b.x); o[5] = f32_to_bf16(b.y);
  o[6] = f32_to_bf16(b.z); o[7] = f32_to_bf16(b.w);
  *(short8*)(xb + (size_t)t * 8) = o;
}

// wqk [1024][128], wv [1024][1024] fp32 -> wT TILED bf16, rows n=0..1151
__global__ __launch_bounds__(256) void k_prep_w(
    const float* __restrict__ wqk, const float* __restrict__ wv,
    uint16_t* __restrict__ wT)
{
  int t = blockIdx.x * 256 + threadIdx.x;      // 0 .. 1152*128-1
  int n16 = t & 15, oct = (t >> 4) & 3, kb = (t >> 6) & 31, nb = t >> 11;
  int n = nb * 16 + n16;
  int k0 = kb * 32 + oct * 8;
  short8 o;
  if (n < DQK) {
    #pragma unroll
    for (int j = 0; j < 8; j++)
      o[j] = f32_to_bf16(wqk[(size_t)(k0 + j) * DQK + n]);
  } else {
    int nn = n - DQK;
    #pragma unroll
    for (int j = 0; j < 8; j++)
      o[j] = f32_to_bf16(wv[(size_t)(k0 + j) * DV + nn]);
  }
  *(short8*)(wT + (size_t)t * 8) = o;
}

// bias_n[n] = rel_bias[bucket(n)] * sqrt(DQK)
__global__ __launch_bounds__(256) void k_bias(
    const float* __restrict__ rel, float* __restrict__ bias_n)
{
  int n = blockIdx.x * blockDim.x + threadIdx.x;
  if (n >= S_) return;
  int bucket;
  if (n < 16) {
    bucket = n;
  } else {
    float tt = logf((float)n * 0.0625f) / 2.0794415416798357f * 16.0f;
    int vl = 16 + (int)tt;
    bucket = vl < 31 ? vl : 31;
  }
  bias_n[n] = rel[bucket] * 11.313708498984761f;
}

// ---- GEMM kernels ----------------------------------------------------------

// fused projections. grid (9, 64). bx==0 -> q/k epilogue; bx>=1 -> v -> vT.
// bx==0 uses SWAPPED operands (A=wT cols, B=xb rows) so the lane holds 4
// consecutive dqk cols -> packed 8B stores into qb/kb TILED layout.
__global__ __launch_bounds__(256, 3) void k_gemm_qkv(
    const uint16_t* __restrict__ xb, const uint16_t* __restrict__ wT,
    const float* __restrict__ bqk, const float* __restrict__ gamma,
    const float* __restrict__ beta, const float* __restrict__ bv,
    uint16_t* __restrict__ qb, uint16_t* __restrict__ kb,
    uint16_t* __restrict__ vT)
{
  int bx = blockIdx.x, by = blockIdx.y;
  WAVE_PREAMBLE
  f32x4 acc[4][4];

  if (bx == 0) {
    // A = wT rows (dqk cols c), B = xb rows (seq i).  acc[mt][nt]:
    // c = (wave>>1)*64 + mt*16 + quad*4 + r,  i = by*128 + (wave&1)*64 + nt*16 + lane16
    wave_gemm_r(wT, DIM_ >> 5, (wave >> 1) * 4,
                xb, DIM_ >> 5, by * 8 + (wave & 1) * 4,
                DIM_ >> 5, acc);
    int ibase = by * 128 + (wave & 1) * 64;
    int cbase = (wave >> 1) * 64;
    #pragma unroll
    for (int mt = 0; mt < 4; mt++) {
      int c0 = cbase + mt * 16 + quad * 4;
      float4 bb = *(const float4*)(bqk + c0);
      float4 g0 = *(const float4*)(gamma + c0);
      float4 g1 = *(const float4*)(gamma + DQK + c0);
      float4 e0 = *(const float4*)(beta + c0);
      float4 e1 = *(const float4*)(beta + DQK + c0);
      size_t coff = (size_t)(c0 >> 5) * 512 + ((c0 >> 3) & 3) * 128 + (c0 & 7);
      #pragma unroll
      for (int nt = 0; nt < 4; nt++) {
        int i = ibase + nt * 16 + lane16;
        float s0 = silu_f(acc[mt][nt][0] + bb.x);
        float s1 = silu_f(acc[mt][nt][1] + bb.y);
        float s2 = silu_f(acc[mt][nt][2] + bb.z);
        float s3 = silu_f(acc[mt][nt][3] + bb.w);
        uint2 pq, pk;
        pq.x = pack_bf16(fmaf(s0, g0.x, e0.x), fmaf(s1, g0.y, e0.y));
        pq.y = pack_bf16(fmaf(s2, g0.z, e0.z), fmaf(s3, g0.w, e0.w));
        pk.x = pack_bf16(fmaf(s0, g1.x, e1.x), fmaf(s1, g1.y, e1.y));
        pk.y = pack_bf16(fmaf(s2, g1.z, e1.z), fmaf(s3, g1.w, e1.w));
        size_t off = (size_t)(i >> 4) * 4 * 512 + (size_t)(i & 15) * 8 + coff;
        *(uint2*)(qb + off) = pq;
        *(uint2*)(kb + off) = pk;
      }
    }
  } else {
    wave_gemm_r(xb, DIM_ >> 5, by * 8 + (wave >> 1) * 4,
                wT, DIM_ >> 5, bx * 8 + (wave & 1) * 4,
                DIM_ >> 5, acc);
    int b = by >> 4;                               // batch (by*128 / 2048)
    uint16_t* vt = vT + (size_t)b * DV * S_;
    #pragma unroll
    for (int nt = 0; nt < 4; nt++) {
      int n = (bx - 1) * 128 + wcol + nt * 16 + lane16;   // 0..1023
      float bb = bv[n];
      #pragma unroll
      for (int mt = 0; mt < 4; mt++) {
        int j0l = (by & 15) * 128 + wrow + mt * 16 + quad * 4; // local seq
        uint16_t v0 = f32_to_bf16(silu_f(acc[mt][nt][0] + bb));
        uint16_t v1 = f32_to_bf16(silu_f(acc[mt][nt][1] + bb));
        uint16_t v2 = f32_to_bf16(silu_f(acc[mt][nt][2] + bb));
        uint16_t v3 = f32_to_bf16(silu_f(acc[mt][nt][3] + bb));
        size_t off = (size_t)((n >> 4) * 64 + (j0l >> 5)) * 512 +
                     ((j0l >> 3) & 3) * 128 + (n & 15) * 8 + (j0l & 7);
        uint2 pk;
        pk.x = (uint32_t)v0 | ((uint32_t)v1 << 16);
        pk.y = (uint32_t)v2 | ((uint32_t)v3 << 16);
        *(uint2*)(vt + off) = pk;
      }
    }
  }
}

// attn = laplacian(q@k^T/S + bias[i-j]) causal, TILED bf16 per batch.
// grid (16, 16, 4): jt, it, b; jt>it skipped (tiles never read downstream).
// SWAPPED: A = kb rows (j), B = qb rows (i) -> lane holds i=lane16 and four
// consecutive j per (mt,quad) -> one packed 8B store each.
__global__ __launch_bounds__(256, 3) void k_gemm_sim(
    const uint16_t* __restrict__ qb, const uint16_t* __restrict__ kb,
    const float* __restrict__ bias_n, uint16_t* __restrict__ attn)
{
  int jt = blockIdx.x, it = blockIdx.y, bt = blockIdx.z;
  if (jt > it) return;
  WAVE_PREAMBLE
  f32x4 acc[4][4];
  wave_gemm_r(kb, 4, bt * 128 + jt * 8 + (wave >> 1) * 4,
              qb, 4, bt * 128 + it * 8 + (wave & 1) * 4,
              4, acc);
  uint16_t* ab = attn + (size_t)bt * S_ * S_;
  int ibase = it * 128 + (wave & 1) * 64;
  int jbase = jt * 128 + (wave >> 1) * 64;
  #pragma unroll
  for (int nt = 0; nt < 4; nt++) {
    int i = ibase + nt * 16 + lane16;
    size_t irow = (size_t)(i >> 4) * 64 * 512 + (size_t)(i & 15) * 8;
    #pragma unroll
    for (int mt = 0; mt < 4; mt++) {
      int j0 = jbase + mt * 16 + quad * 4;
      float v[4];
      #pragma unroll
      for (int r = 0; r < 4; r++) {
        int j = j0 + r;
        float aval = 0.0f;
        if (j <= i) {
          float sim = acc[mt][nt][r] * (1.0f / 2048.0f) + bias_n[i - j];
          aval = laplacian_attn(sim);
        }
        v[r] = aval;
      }
      uint2 pk;
      pk.x = pack_bf16(v[0], v[1]);
      pk.y = pack_bf16(v[2], v[3]);
      size_t off = irow + (size_t)(j0 >> 5) * 512 + ((j0 >> 3) & 3) * 128 +
                   (j0 & 7);
      *(uint2*)(ab + off) = pk;
    }
  }
}

// out = attn @ v, fp32 out. grid (8, 64): y = bt*16 + tt, it balanced so
// co-resident groups get ~constant K; nkb = 4*it+4 (causal bound).
__global__ __launch_bounds__(256, 3) void k_gemm_out(
    const uint16_t* __restrict__ attn, const uint16_t* __restrict__ vT,
    float* __restrict__ out)
{
  int nx = blockIdx.x;
  int y = blockIdx.y;
  int bt = y >> 4, tt = y & 15;
  int it = (bt & 1) ? (15 - tt) : tt;
  int nkb = 4 * it + 4;
  WAVE_PREAMBLE
  f32x4 acc[4][4];
  wave_gemm_r(attn + (size_t)bt * S_ * S_, 64, it * 8 + (wave >> 1) * 4,
              vT + (size_t)bt * DV * S_, 64, nx * 8 + (wave & 1) * 4,
              nkb, acc);
  #pragma unroll
  for (int mt = 0; mt < 4; mt++)
    #pragma unroll
    for (int nt = 0; nt < 4; nt++)
      #pragma unroll
      for (int r = 0; r < 4; r++) {
        int i = it * 128 + wrow + mt * 16 + quad * 4 + r;
        int n = nx * 128 + wcol + nt * 16 + lane16;
        out[((size_t)bt * S_ + i) * DV + n] = acc[mt][nt][r];
      }
}

// ---------------------------------------------------------------------------

extern "C" void kernel_launch(void* const* d_in, const int* in_sizes, int n_in,
                              void* d_out, int out_size, void* d_ws, size_t ws_size,
                              hipStream_t stream)
{
  const float* x     = (const float*)d_in[0];
  const float* wqk   = (const float*)d_in[1];
  const float* bqk   = (const float*)d_in[2];
  const float* gamma = (const float*)d_in[3];
  const float* beta  = (const float*)d_in[4];
  const float* wv    = (const float*)d_in[5];
  const float* bv    = (const float*)d_in[6];
  const float* rel   = (const float*)d_in[7];
  float* out = (float*)d_out;

  char* ws = (char*)d_ws;
  size_t off = 0;
  uint16_t* xb     = (uint16_t*)(ws + off); off += (size_t)B_ * S_ * DIM_ * 2;  // 16 MB
  uint16_t* wT     = (uint16_t*)(ws + off); off += (size_t)NQV * DIM_ * 2;      // 2.25 MB
  uint16_t* qb     = (uint16_t*)(ws + off); off += (size_t)B_ * S_ * DQK * 2;   // 2 MB
  uint16_t* kb     = (uint16_t*)(ws + off); off += (size_t)B_ * S_ * DQK * 2;   // 2 MB
  uint16_t* vT     = (uint16_t*)(ws + off); off += (size_t)B_ * DV * S_ * 2;    // 16 MB
  uint16_t* attn   = (uint16_t*)(ws + off); off += (size_t)B_ * S_ * S_ * 2;    // 32 MB
  float*    bias_n = (float*)(ws + off);    off += (size_t)S_ * 4;              // 8 KB

  k_prep_x<<<dim3(B_ * S_ * DIM_ / 8 / 256), dim3(256), 0, stream>>>(x, xb);
  k_prep_w<<<dim3(NQV * DIM_ / 8 / 256), dim3(256), 0, stream>>>(wqk, wv, wT);
  k_bias<<<dim3(S_ / 256), dim3(256), 0, stream>>>(rel, bias_n);

  k_gemm_qkv<<<dim3(NQV / 128, B_ * S_ / 128), dim3(256), 0, stream>>>(
      xb, wT, bqk, gamma, beta, bv, qb, kb, vT);
  k_gemm_sim<<<dim3(S_ / 128, S_ / 128, B_), dim3(256), 0, stream>>>(
      qb, kb, bias_n, attn);
  k_gemm_out<<<dim3(DV / 128, B_ * S_ / 128), dim3(256), 0, stream>>>(
      attn, vT, out);
}

// Round 3
// 196.391 us; speedup vs baseline: 1.1513x; 1.0524x over previous
//
#include <hip/hip_runtime.h>
#include <stdint.h>

// ---------------------------------------------------------------------------
// SingleHeadedAttention (Mega-style, laplacian attn fn, causal, T5 rel bias)
// B=4, S=2048, DIM=1024, DQK=128, DV=1024.  fp32 in/out, bf16 MFMA internals.
// R11: sim is latency-bound with ~1 wave/SIMD (occupancy 13%, MfmaUtil 1.7%,
//   VALUBusy 12%, nothing saturated; ~23.5us residency per wave). Fix = TLP:
//   - sim per-wave tile 64x64 -> 32x64 (acc[4][2]), 128-thread blocks (2
//     waves), exact causal triangle grid (528 tiles/batch, no dead blocks),
//     __launch_bounds__(128,4) -> ~4 waves/SIMD co-resident.
//   - wave_gemm templated <MT,NT>; qkv/out keep <4,4> behavior unchanged.
// R10: fast branchless erf; swapped QK^T in sim (packed 8B stores); swapped
//   q/k projection epilogue; native-exp silu.
//   TILED: element (row,k) of [R][K] at
//     ((row>>4)*(K>>5) + (k>>5))*512 + ((k>>3)&3)*128 + (row&15)*8 + (k&7).
//   Lane l's MFMA fragment of a 16x32 block = 16 contiguous bytes at
//   base + l*16 -> one coalesced global_load_dwordx4 per fragment. No LDS,
//   no barriers, no DMA in the GEMMs; register double-buffer (2 k-blocks).
// ---------------------------------------------------------------------------

#define B_   4
#define S_   2048
#define DIM_ 1024
#define DQK  128
#define DV   1024
#define NQV  1152

typedef __attribute__((ext_vector_type(8))) short short8;   // 8 bf16
typedef __attribute__((ext_vector_type(4))) float f32x4;    // MFMA C/D

__device__ __forceinline__ uint16_t f32_to_bf16(float f) {
  uint32_t u = __float_as_uint(f);
  u += 0x7FFFu + ((u >> 16) & 1u);          // round-to-nearest-even
  return (uint16_t)(u >> 16);
}

__device__ __forceinline__ uint32_t pack_bf16(float a, float b) {
  return (uint32_t)f32_to_bf16(a) | ((uint32_t)f32_to_bf16(b) << 16);
}

__device__ __forceinline__ float silu_f(float x) {
  // x * sigmoid(x), native exp + v_rcp (bf16 output tolerates ~1e-6 rel err)
  return x * __builtin_amdgcn_rcpf(1.0f + __expf(-x));
}

// 0.5*(1+erf((x-mu)/(std*sqrt2))), mu=sqrt(0.5), std=sqrt(pi/4).
// Branchless Abramowitz-Stegun 7.1.26 erf approx, |eps| <= 1.5e-7.
__device__ __forceinline__ float laplacian_attn(float x) {
  float z  = (x - 0.70710678118654752f) * 0.79788456080286536f;
  float az = fabsf(z);
  float t  = __builtin_amdgcn_rcpf(fmaf(0.3275911f, az, 1.0f));
  float w  = fmaf(1.061405429f, t, -1.453152027f);
  w = fmaf(w, t, 1.421413741f);
  w = fmaf(w, t, -0.284496736f);
  w = fmaf(w, t, 0.254829592f);
  float P  = w * t;
  float E  = __expf(-z * z);
  float ea = fmaf(-P, E, 1.0f);            // erf(|z|)
  float er = copysignf(ea, z);
  return fmaf(0.5f, er, 0.5f);
}

// ---- wave-private MTx NT (16-row units) GEMM on TILED operands ------------
// A tiled [RA][K] row-blocks rbA..+MT-1, Bt tiled [RB][K] rbB..+NT-1.
// KBa/KBb = K>>5. nkb even, >=2. Fragments global->VGPR, contiguous 16B/lane.
template <int MT, int NT>
__device__ __forceinline__ void wave_gemm_t(
    const uint16_t* __restrict__ A, int KBa, int rbA,
    const uint16_t* __restrict__ Bt, int KBb, int rbB,
    int nkb, f32x4 acc[MT][NT])
{
  const int lane = threadIdx.x & 63;

  const uint16_t* pa[MT];
  const uint16_t* pb[NT];
  #pragma unroll
  for (int mt = 0; mt < MT; mt++)
    pa[mt] = A + (size_t)(rbA + mt) * KBa * 512 + lane * 8;
  #pragma unroll
  for (int nt = 0; nt < NT; nt++)
    pb[nt] = Bt + (size_t)(rbB + nt) * KBb * 512 + lane * 8;

  #pragma unroll
  for (int mt = 0; mt < MT; mt++)
    #pragma unroll
    for (int nt = 0; nt < NT; nt++) {
      f32x4 z = {0.0f, 0.0f, 0.0f, 0.0f};
      acc[mt][nt] = z;
    }

  short8 fa0[MT], fb0[NT], fa1[MT], fb1[NT];

  auto loads = [&](short8 fa[MT], short8 fb[NT], int kb) {
    #pragma unroll
    for (int mt = 0; mt < MT; mt++)
      fa[mt] = *(const short8*)(pa[mt] + (size_t)kb * 512);
    #pragma unroll
    for (int nt = 0; nt < NT; nt++)
      fb[nt] = *(const short8*)(pb[nt] + (size_t)kb * 512);
  };
  auto mfmas = [&](short8 fa[MT], short8 fb[NT]) {
    #pragma unroll
    for (int mt = 0; mt < MT; mt++)
      #pragma unroll
      for (int nt = 0; nt < NT; nt++)
        acc[mt][nt] = __builtin_amdgcn_mfma_f32_16x16x32_bf16(
            fa[mt], fb[nt], acc[mt][nt], 0, 0, 0);
  };

  loads(fa0, fb0, 0);
  loads(fa1, fb1, 1);
  for (int kb = 2; kb < nkb; kb += 2) {
    mfmas(fa0, fb0);
    loads(fa0, fb0, kb);
    mfmas(fa1, fb1);
    loads(fa1, fb1, kb + 1);
  }
  mfmas(fa0, fb0);
  mfmas(fa1, fb1);
}

// 256-thread block = 4 independent waves over a 128x128 tile.
// wave w: rows +(w>>1)*64 (row-blocks +(w>>1)*4), cols +(w&1)*64.
#define WAVE_PREAMBLE                                  \
  int lane = threadIdx.x & 63;                         \
  int wave = threadIdx.x >> 6;                         \
  int lane16 = lane & 15;                              \
  int quad = lane >> 4;                                \
  int wrow = (wave >> 1) * 64;                         \
  int wcol = (wave & 1) * 64;

// ---- prep kernels ----------------------------------------------------------

// x fp32 [8192][1024] -> xb TILED bf16 (output linear/coalesced).
__global__ __launch_bounds__(256) void k_prep_x(
    const float* __restrict__ x, uint16_t* __restrict__ xb)
{
  int t = blockIdx.x * 256 + threadIdx.x;      // 0 .. 8192*128-1
  int i16 = t & 15, oct = (t >> 4) & 3, kb = (t >> 6) & 31, ib = t >> 11;
  const float* src = x + (size_t)(ib * 16 + i16) * DIM_ + kb * 32 + oct * 8;
  float4 a = *(const float4*)src;
  float4 b = *(const float4*)(src + 4);
  short8 o;
  o[0] = f32_to_bf16(a.x); o[1] = f32_to_bf16(a.y);
  o[2] = f32_to_bf16(a.z); o[3] = f32_to_bf16(a.w);
  o[4] = f32_to_bf16(b.x); o[5] = f32_to_bf16(b.y);
  o[6] = f32_to_bf16(b.z); o[7] = f32_to_bf16(b.w);
  *(short8*)(xb + (size_t)t * 8) = o;
}

// wqk [1024][128], wv [1024][1024] fp32 -> wT TILED bf16, rows n=0..1151
__global__ __launch_bounds__(256) void k_prep_w(
    const float* __restrict__ wqk, const float* __restrict__ wv,
    uint16_t* __restrict__ wT)
{
  int t = blockIdx.x * 256 + threadIdx.x;      // 0 .. 1152*128-1
  int n16 = t & 15, oct = (t >> 4) & 3, kb = (t >> 6) & 31, nb = t >> 11;
  int n = nb * 16 + n16;
  int k0 = kb * 32 + oct * 8;
  short8 o;
  if (n < DQK) {
    #pragma unroll
    for (int j = 0; j < 8; j++)
      o[j] = f32_to_bf16(wqk[(size_t)(k0 + j) * DQK + n]);
  } else {
    int nn = n - DQK;
    #pragma unroll
    for (int j = 0; j < 8; j++)
      o[j] = f32_to_bf16(wv[(size_t)(k0 + j) * DV + nn]);
  }
  *(short8*)(wT + (size_t)t * 8) = o;
}

// bias_n[n] = rel_bias[bucket(n)] * sqrt(DQK)
__global__ __launch_bounds__(256) void k_bias(
    const float* __restrict__ rel, float* __restrict__ bias_n)
{
  int n = blockIdx.x * blockDim.x + threadIdx.x;
  if (n >= S_) return;
  int bucket;
  if (n < 16) {
    bucket = n;
  } else {
    float tt = logf((float)n * 0.0625f) / 2.0794415416798357f * 16.0f;
    int vl = 16 + (int)tt;
    bucket = vl < 31 ? vl : 31;
  }
  bias_n[n] = rel[bucket] * 11.313708498984761f;
}

// ---- GEMM kernels ----------------------------------------------------------

// fused projections. grid (9, 64). bx==0 -> q/k epilogue; bx>=1 -> v -> vT.
// bx==0 uses SWAPPED operands (A=wT cols, B=xb rows) so the lane holds 4
// consecutive dqk cols -> packed 8B stores into qb/kb TILED layout.
__global__ __launch_bounds__(256, 3) void k_gemm_qkv(
    const uint16_t* __restrict__ xb, const uint16_t* __restrict__ wT,
    const float* __restrict__ bqk, const float* __restrict__ gamma,
    const float* __restrict__ beta, const float* __restrict__ bv,
    uint16_t* __restrict__ qb, uint16_t* __restrict__ kb,
    uint16_t* __restrict__ vT)
{
  int bx = blockIdx.x, by = blockIdx.y;
  WAVE_PREAMBLE
  f32x4 acc[4][4];

  if (bx == 0) {
    // A = wT rows (dqk cols c), B = xb rows (seq i).  acc[mt][nt]:
    // c = (wave>>1)*64 + mt*16 + quad*4 + r,  i = by*128 + (wave&1)*64 + nt*16 + lane16
    wave_gemm_t<4,4>(wT, DIM_ >> 5, (wave >> 1) * 4,
                     xb, DIM_ >> 5, by * 8 + (wave & 1) * 4,
                     DIM_ >> 5, acc);
    int ibase = by * 128 + (wave & 1) * 64;
    int cbase = (wave >> 1) * 64;
    #pragma unroll
    for (int mt = 0; mt < 4; mt++) {
      int c0 = cbase + mt * 16 + quad * 4;
      float4 bb = *(const float4*)(bqk + c0);
      float4 g0 = *(const float4*)(gamma + c0);
      float4 g1 = *(const float4*)(gamma + DQK + c0);
      float4 e0 = *(const float4*)(beta + c0);
      float4 e1 = *(const float4*)(beta + DQK + c0);
      size_t coff = (size_t)(c0 >> 5) * 512 + ((c0 >> 3) & 3) * 128 + (c0 & 7);
      #pragma unroll
      for (int nt = 0; nt < 4; nt++) {
        int i = ibase + nt * 16 + lane16;
        float s0 = silu_f(acc[mt][nt][0] + bb.x);
        float s1 = silu_f(acc[mt][nt][1] + bb.y);
        float s2 = silu_f(acc[mt][nt][2] + bb.z);
        float s3 = silu_f(acc[mt][nt][3] + bb.w);
        uint2 pq, pk;
        pq.x = pack_bf16(fmaf(s0, g0.x, e0.x), fmaf(s1, g0.y, e0.y));
        pq.y = pack_bf16(fmaf(s2, g0.z, e0.z), fmaf(s3, g0.w, e0.w));
        pk.x = pack_bf16(fmaf(s0, g1.x, e1.x), fmaf(s1, g1.y, e1.y));
        pk.y = pack_bf16(fmaf(s2, g1.z, e1.z), fmaf(s3, g1.w, e1.w));
        size_t off = (size_t)(i >> 4) * 4 * 512 + (size_t)(i & 15) * 8 + coff;
        *(uint2*)(qb + off) = pq;
        *(uint2*)(kb + off) = pk;
      }
    }
  } else {
    wave_gemm_t<4,4>(xb, DIM_ >> 5, by * 8 + (wave >> 1) * 4,
                     wT, DIM_ >> 5, bx * 8 + (wave & 1) * 4,
                     DIM_ >> 5, acc);
    int b = by >> 4;                               // batch (by*128 / 2048)
    uint16_t* vt = vT + (size_t)b * DV * S_;
    #pragma unroll
    for (int nt = 0; nt < 4; nt++) {
      int n = (bx - 1) * 128 + wcol + nt * 16 + lane16;   // 0..1023
      float bb = bv[n];
      #pragma unroll
      for (int mt = 0; mt < 4; mt++) {
        int j0l = (by & 15) * 128 + wrow + mt * 16 + quad * 4; // local seq
        uint16_t v0 = f32_to_bf16(silu_f(acc[mt][nt][0] + bb));
        uint16_t v1 = f32_to_bf16(silu_f(acc[mt][nt][1] + bb));
        uint16_t v2 = f32_to_bf16(silu_f(acc[mt][nt][2] + bb));
        uint16_t v3 = f32_to_bf16(silu_f(acc[mt][nt][3] + bb));
        size_t off = (size_t)((n >> 4) * 64 + (j0l >> 5)) * 512 +
                     ((j0l >> 3) & 3) * 128 + (n & 15) * 8 + (j0l & 7);
        uint2 pk;
        pk.x = (uint32_t)v0 | ((uint32_t)v1 << 16);
        pk.y = (uint32_t)v2 | ((uint32_t)v3 << 16);
        *(uint2*)(vt + off) = pk;
      }
    }
  }
}

// attn = laplacian(q@k^T/S + bias[i-j]) causal, TILED bf16 per batch.
// R11: 64x64 tile per 128-thread block (2 waves, each 32 i-rows x 64 j-cols),
// exact causal triangle grid (528 tiles/batch). SWAPPED: A = kb rows (j),
// B = qb rows (i) -> lane holds i=lane16 and four consecutive j per
// (mt,quad) -> one packed 8B store each.
__global__ __launch_bounds__(128, 4) void k_gemm_sim(
    const uint16_t* __restrict__ qb, const uint16_t* __restrict__ kb,
    const float* __restrict__ bias_n, uint16_t* __restrict__ attn)
{
  int b = blockIdx.x;                    // 0..527 triangular tile index
  int bt = blockIdx.y;                   // batch
  int it = (int)((sqrtf(8.0f * (float)b + 1.0f) - 1.0f) * 0.5f);
  while ((it + 1) * (it + 2) / 2 <= b) ++it;
  while (it * (it + 1) / 2 > b) --it;
  int jt = b - it * (it + 1) / 2;        // 0..it

  int lane = threadIdx.x & 63;
  int wave = threadIdx.x >> 6;           // 0..1 (i-halves of the 64-row tile)
  int lane16 = lane & 15;
  int quad = lane >> 4;

  f32x4 acc[4][2];
  wave_gemm_t<4,2>(kb, 4, bt * 128 + jt * 4,
                   qb, 4, bt * 128 + it * 4 + wave * 2,
                   4, acc);

  uint16_t* ab = attn + (size_t)bt * S_ * S_;
  int ibase = it * 64 + wave * 32;
  int jbase = jt * 64;
  #pragma unroll
  for (int nt = 0; nt < 2; nt++) {
    int i = ibase + nt * 16 + lane16;
    size_t irow = (size_t)(i >> 4) * 64 * 512 + (size_t)(i & 15) * 8;
    #pragma unroll
    for (int mt = 0; mt < 4; mt++) {
      int j0 = jbase + mt * 16 + quad * 4;
      float v[4];
      #pragma unroll
      for (int r = 0; r < 4; r++) {
        int j = j0 + r;
        float aval = 0.0f;
        if (j <= i) {
          float sim = acc[mt][nt][r] * (1.0f / 2048.0f) + bias_n[i - j];
          aval = laplacian_attn(sim);
        }
        v[r] = aval;
      }
      uint2 pk;
      pk.x = pack_bf16(v[0], v[1]);
      pk.y = pack_bf16(v[2], v[3]);
      size_t off = irow + (size_t)(j0 >> 5) * 512 + ((j0 >> 3) & 3) * 128 +
                   (j0 & 7);
      *(uint2*)(ab + off) = pk;
    }
  }
}

// out = attn @ v, fp32 out. grid (8, 64): y = bt*16 + tt, it balanced so
// co-resident groups get ~constant K; nkb = 4*it+4 (causal bound).
__global__ __launch_bounds__(256, 3) void k_gemm_out(
    const uint16_t* __restrict__ attn, const uint16_t* __restrict__ vT,
    float* __restrict__ out)
{
  int nx = blockIdx.x;
  int y = blockIdx.y;
  int bt = y >> 4, tt = y & 15;
  int it = (bt & 1) ? (15 - tt) : tt;
  int nkb = 4 * it + 4;
  WAVE_PREAMBLE
  f32x4 acc[4][4];
  wave_gemm_t<4,4>(attn + (size_t)bt * S_ * S_, 64, it * 8 + (wave >> 1) * 4,
                   vT + (size_t)bt * DV * S_, 64, nx * 8 + (wave & 1) * 4,
                   nkb, acc);
  #pragma unroll
  for (int mt = 0; mt < 4; mt++)
    #pragma unroll
    for (int nt = 0; nt < 4; nt++)
      #pragma unroll
      for (int r = 0; r < 4; r++) {
        int i = it * 128 + wrow + mt * 16 + quad * 4 + r;
        int n = nx * 128 + wcol + nt * 16 + lane16;
        out[((size_t)bt * S_ + i) * DV + n] = acc[mt][nt][r];
      }
}

// ---------------------------------------------------------------------------

extern "C" void kernel_launch(void* const* d_in, const int* in_sizes, int n_in,
                              void* d_out, int out_size, void* d_ws, size_t ws_size,
                              hipStream_t stream)
{
  const float* x     = (const float*)d_in[0];
  const float* wqk   = (const float*)d_in[1];
  const float* bqk   = (const float*)d_in[2];
  const float* gamma = (const float*)d_in[3];
  const float* beta  = (const float*)d_in[4];
  const float* wv    = (const float*)d_in[5];
  const float* bv    = (const float*)d_in[6];
  const float* rel   = (const float*)d_in[7];
  float* out = (float*)d_out;

  char* ws = (char*)d_ws;
  size_t off = 0;
  uint16_t* xb     = (uint16_t*)(ws + off); off += (size_t)B_ * S_ * DIM_ * 2;  // 16 MB
  uint16_t* wT     = (uint16_t*)(ws + off); off += (size_t)NQV * DIM_ * 2;      // 2.25 MB
  uint16_t* qb     = (uint16_t*)(ws + off); off += (size_t)B_ * S_ * DQK * 2;   // 2 MB
  uint16_t* kb     = (uint16_t*)(ws + off); off += (size_t)B_ * S_ * DQK * 2;   // 2 MB
  uint16_t* vT     = (uint16_t*)(ws + off); off += (size_t)B_ * DV * S_ * 2;    // 16 MB
  uint16_t* attn   = (uint16_t*)(ws + off); off += (size_t)B_ * S_ * S_ * 2;    // 32 MB
  float*    bias_n = (float*)(ws + off);    off += (size_t)S_ * 4;              // 8 KB

  k_prep_x<<<dim3(B_ * S_ * DIM_ / 8 / 256), dim3(256), 0, stream>>>(x, xb);
  k_prep_w<<<dim3(NQV * DIM_ / 8 / 256), dim3(256), 0, stream>>>(wqk, wv, wT);
  k_bias<<<dim3(S_ / 256), dim3(256), 0, stream>>>(rel, bias_n);

  k_gemm_qkv<<<dim3(NQV / 128, B_ * S_ / 128), dim3(256), 0, stream>>>(
      xb, wT, bqk, gamma, beta, bv, qb, kb, vT);
  k_gemm_sim<<<dim3(528, B_), dim3(128), 0, stream>>>(
      qb, kb, bias_n, attn);
  k_gemm_out<<<dim3(DV / 128, B_ * S_ / 128), dim3(256), 0, stream>>>(
      attn, vT, out);
}

// Round 4
// 190.746 us; speedup vs baseline: 1.1854x; 1.0296x over previous
//
#include <hip/hip_runtime.h>
#include <stdint.h>

// ---------------------------------------------------------------------------
// SingleHeadedAttention (Mega-style, laplacian attn fn, causal, T5 rel bias)
// B=4, S=2048, DIM=1024, DQK=128, DV=1024.  fp32 in/out, bf16 MFMA internals.
// R12: k_gemm_out 45.4us @ MfmaUtil 14% / occ 10% -> latency(2-deep buffer
//   exposes ~460cyc/kb-iter) + causal imbalance (K 4..64 kb). Fixes:
//   - 4-deep register pipeline (DEPTH=4) for out+qkv: one latency exposure
//     per 4 kb; launch_bounds (256,2) for regalloc room.
//   - out: LPT + XCD-swizzled 1-D grid (heavy it first; all it-blocks of a
//     (bt,nx) group on one XCD -> vT panel L2-resident).
//   - out: swapped operands (A=vT n-rows, B=attn i-rows) -> acc holds 4
//     consecutive n -> float4 epilogue stores (16/thread vs 64 scalar).
//   sim unchanged from R11 (2-deep, (128,4)).
// R11: sim TLP fix (32x64 wave tiles, 128-thr blocks, exact triangle grid).
// R10: fast branchless erf; swapped QK^T in sim; swapped q/k proj epilogue.
//   TILED: element (row,k) of [R][K] at
//     ((row>>4)*(K>>5) + (k>>5))*512 + ((k>>3)&3)*128 + (row&15)*8 + (k&7).
//   Lane l's MFMA fragment of a 16x32 block = 16 contiguous bytes at
//   base + l*16 -> one coalesced global_load_dwordx4 per fragment. No LDS,
//   no barriers, no DMA in the GEMMs.
// ---------------------------------------------------------------------------

#define B_   4
#define S_   2048
#define DIM_ 1024
#define DQK  128
#define DV   1024
#define NQV  1152

typedef __attribute__((ext_vector_type(8))) short short8;   // 8 bf16
typedef __attribute__((ext_vector_type(4))) float f32x4;    // MFMA C/D

__device__ __forceinline__ uint16_t f32_to_bf16(float f) {
  uint32_t u = __float_as_uint(f);
  u += 0x7FFFu + ((u >> 16) & 1u);          // round-to-nearest-even
  return (uint16_t)(u >> 16);
}

__device__ __forceinline__ uint32_t pack_bf16(float a, float b) {
  return (uint32_t)f32_to_bf16(a) | ((uint32_t)f32_to_bf16(b) << 16);
}

__device__ __forceinline__ float silu_f(float x) {
  // x * sigmoid(x), native exp + v_rcp (bf16 output tolerates ~1e-6 rel err)
  return x * __builtin_amdgcn_rcpf(1.0f + __expf(-x));
}

// 0.5*(1+erf((x-mu)/(std*sqrt2))), mu=sqrt(0.5), std=sqrt(pi/4).
// Branchless Abramowitz-Stegun 7.1.26 erf approx, |eps| <= 1.5e-7.
__device__ __forceinline__ float laplacian_attn(float x) {
  float z  = (x - 0.70710678118654752f) * 0.79788456080286536f;
  float az = fabsf(z);
  float t  = __builtin_amdgcn_rcpf(fmaf(0.3275911f, az, 1.0f));
  float w  = fmaf(1.061405429f, t, -1.453152027f);
  w = fmaf(w, t, 1.421413741f);
  w = fmaf(w, t, -0.284496736f);
  w = fmaf(w, t, 0.254829592f);
  float P  = w * t;
  float E  = __expf(-z * z);
  float ea = fmaf(-P, E, 1.0f);            // erf(|z|)
  float er = copysignf(ea, z);
  return fmaf(0.5f, er, 0.5f);
}

// ---- wave-private MTxNT (16-row units) GEMM on TILED operands -------------
// A tiled [RA][K] row-blocks rbA..+MT-1, Bt tiled [RB][K] rbB..+NT-1.
// KBa/KBb = K>>5. DEPTH=2: nkb even >=2. DEPTH=4: nkb multiple of 4 >=4.
// Fragments global->VGPR, contiguous 16B/lane.
template <int MT, int NT, int DEPTH>
__device__ __forceinline__ void wave_gemm_t(
    const uint16_t* __restrict__ A, int KBa, int rbA,
    const uint16_t* __restrict__ Bt, int KBb, int rbB,
    int nkb, f32x4 acc[MT][NT])
{
  const int lane = threadIdx.x & 63;

  const uint16_t* pa[MT];
  const uint16_t* pb[NT];
  #pragma unroll
  for (int mt = 0; mt < MT; mt++)
    pa[mt] = A + (size_t)(rbA + mt) * KBa * 512 + lane * 8;
  #pragma unroll
  for (int nt = 0; nt < NT; nt++)
    pb[nt] = Bt + (size_t)(rbB + nt) * KBb * 512 + lane * 8;

  #pragma unroll
  for (int mt = 0; mt < MT; mt++)
    #pragma unroll
    for (int nt = 0; nt < NT; nt++) {
      f32x4 z = {0.0f, 0.0f, 0.0f, 0.0f};
      acc[mt][nt] = z;
    }

  short8 fa0[MT], fb0[NT], fa1[MT], fb1[NT];

  auto loads = [&](short8 fa[MT], short8 fb[NT], int kb) {
    #pragma unroll
    for (int mt = 0; mt < MT; mt++)
      fa[mt] = *(const short8*)(pa[mt] + (size_t)kb * 512);
    #pragma unroll
    for (int nt = 0; nt < NT; nt++)
      fb[nt] = *(const short8*)(pb[nt] + (size_t)kb * 512);
  };
  auto mfmas = [&](short8 fa[MT], short8 fb[NT]) {
    #pragma unroll
    for (int mt = 0; mt < MT; mt++)
      #pragma unroll
      for (int nt = 0; nt < NT; nt++)
        acc[mt][nt] = __builtin_amdgcn_mfma_f32_16x16x32_bf16(
            fa[mt], fb[nt], acc[mt][nt], 0, 0, 0);
  };

  if constexpr (DEPTH == 2) {
    loads(fa0, fb0, 0);
    loads(fa1, fb1, 1);
    for (int kb = 2; kb < nkb; kb += 2) {
      mfmas(fa0, fb0);
      loads(fa0, fb0, kb);
      mfmas(fa1, fb1);
      loads(fa1, fb1, kb + 1);
    }
    mfmas(fa0, fb0);
    mfmas(fa1, fb1);
  } else {
    short8 fa2[MT], fb2[NT], fa3[MT], fb3[NT];
    loads(fa0, fb0, 0);
    loads(fa1, fb1, 1);
    loads(fa2, fb2, 2);
    loads(fa3, fb3, 3);
    for (int kb = 4; kb < nkb; kb += 4) {
      mfmas(fa0, fb0);
      loads(fa0, fb0, kb);
      mfmas(fa1, fb1);
      loads(fa1, fb1, kb + 1);
      mfmas(fa2, fb2);
      loads(fa2, fb2, kb + 2);
      mfmas(fa3, fb3);
      loads(fa3, fb3, kb + 3);
    }
    mfmas(fa0, fb0);
    mfmas(fa1, fb1);
    mfmas(fa2, fb2);
    mfmas(fa3, fb3);
  }
}

// 256-thread block = 4 independent waves over a 128x128 tile.
// wave w: rows +(w>>1)*64 (row-blocks +(w>>1)*4), cols +(w&1)*64.
#define WAVE_PREAMBLE                                  \
  int lane = threadIdx.x & 63;                         \
  int wave = threadIdx.x >> 6;                         \
  int lane16 = lane & 15;                              \
  int quad = lane >> 4;                                \
  int wrow = (wave >> 1) * 64;                         \
  int wcol = (wave & 1) * 64;

// ---- prep kernels ----------------------------------------------------------

// x fp32 [8192][1024] -> xb TILED bf16 (output linear/coalesced).
__global__ __launch_bounds__(256) void k_prep_x(
    const float* __restrict__ x, uint16_t* __restrict__ xb)
{
  int t = blockIdx.x * 256 + threadIdx.x;      // 0 .. 8192*128-1
  int i16 = t & 15, oct = (t >> 4) & 3, kb = (t >> 6) & 31, ib = t >> 11;
  const float* src = x + (size_t)(ib * 16 + i16) * DIM_ + kb * 32 + oct * 8;
  float4 a = *(const float4*)src;
  float4 b = *(const float4*)(src + 4);
  short8 o;
  o[0] = f32_to_bf16(a.x); o[1] = f32_to_bf16(a.y);
  o[2] = f32_to_bf16(a.z); o[3] = f32_to_bf16(a.w);
  o[4] = f32_to_bf16(b.x); o[5] = f32_to_bf16(b.y);
  o[6] = f32_to_bf16(b.z); o[7] = f32_to_bf16(b.w);
  *(short8*)(xb + (size_t)t * 8) = o;
}

// wqk [1024][128], wv [1024][1024] fp32 -> wT TILED bf16, rows n=0..1151
__global__ __launch_bounds__(256) void k_prep_w(
    const float* __restrict__ wqk, const float* __restrict__ wv,
    uint16_t* __restrict__ wT)
{
  int t = blockIdx.x * 256 + threadIdx.x;      // 0 .. 1152*128-1
  int n16 = t & 15, oct = (t >> 4) & 3, kb = (t >> 6) & 31, nb = t >> 11;
  int n = nb * 16 + n16;
  int k0 = kb * 32 + oct * 8;
  short8 o;
  if (n < DQK) {
    #pragma unroll
    for (int j = 0; j < 8; j++)
      o[j] = f32_to_bf16(wqk[(size_t)(k0 + j) * DQK + n]);
  } else {
    int nn = n - DQK;
    #pragma unroll
    for (int j = 0; j < 8; j++)
      o[j] = f32_to_bf16(wv[(size_t)(k0 + j) * DV + nn]);
  }
  *(short8*)(wT + (size_t)t * 8) = o;
}

// bias_n[n] = rel_bias[bucket(n)] * sqrt(DQK)
__global__ __launch_bounds__(256) void k_bias(
    const float* __restrict__ rel, float* __restrict__ bias_n)
{
  int n = blockIdx.x * blockDim.x + threadIdx.x;
  if (n >= S_) return;
  int bucket;
  if (n < 16) {
    bucket = n;
  } else {
    float tt = logf((float)n * 0.0625f) / 2.0794415416798357f * 16.0f;
    int vl = 16 + (int)tt;
    bucket = vl < 31 ? vl : 31;
  }
  bias_n[n] = rel[bucket] * 11.313708498984761f;
}

// ---- GEMM kernels ----------------------------------------------------------

// fused projections. grid (9, 64). bx==0 -> q/k epilogue; bx>=1 -> v -> vT.
// bx==0 uses SWAPPED operands (A=wT cols, B=xb rows) so the lane holds 4
// consecutive dqk cols -> packed 8B stores into qb/kb TILED layout.
__global__ __launch_bounds__(256, 2) void k_gemm_qkv(
    const uint16_t* __restrict__ xb, const uint16_t* __restrict__ wT,
    const float* __restrict__ bqk, const float* __restrict__ gamma,
    const float* __restrict__ beta, const float* __restrict__ bv,
    uint16_t* __restrict__ qb, uint16_t* __restrict__ kb,
    uint16_t* __restrict__ vT)
{
  int bx = blockIdx.x, by = blockIdx.y;
  WAVE_PREAMBLE
  f32x4 acc[4][4];

  if (bx == 0) {
    // A = wT rows (dqk cols c), B = xb rows (seq i).  acc[mt][nt]:
    // c = (wave>>1)*64 + mt*16 + quad*4 + r,  i = by*128 + (wave&1)*64 + nt*16 + lane16
    wave_gemm_t<4,4,4>(wT, DIM_ >> 5, (wave >> 1) * 4,
                       xb, DIM_ >> 5, by * 8 + (wave & 1) * 4,
                       DIM_ >> 5, acc);
    int ibase = by * 128 + (wave & 1) * 64;
    int cbase = (wave >> 1) * 64;
    #pragma unroll
    for (int mt = 0; mt < 4; mt++) {
      int c0 = cbase + mt * 16 + quad * 4;
      float4 bb = *(const float4*)(bqk + c0);
      float4 g0 = *(const float4*)(gamma + c0);
      float4 g1 = *(const float4*)(gamma + DQK + c0);
      float4 e0 = *(const float4*)(beta + c0);
      float4 e1 = *(const float4*)(beta + DQK + c0);
      size_t coff = (size_t)(c0 >> 5) * 512 + ((c0 >> 3) & 3) * 128 + (c0 & 7);
      #pragma unroll
      for (int nt = 0; nt < 4; nt++) {
        int i = ibase + nt * 16 + lane16;
        float s0 = silu_f(acc[mt][nt][0] + bb.x);
        float s1 = silu_f(acc[mt][nt][1] + bb.y);
        float s2 = silu_f(acc[mt][nt][2] + bb.z);
        float s3 = silu_f(acc[mt][nt][3] + bb.w);
        uint2 pq, pk;
        pq.x = pack_bf16(fmaf(s0, g0.x, e0.x), fmaf(s1, g0.y, e0.y));
        pq.y = pack_bf16(fmaf(s2, g0.z, e0.z), fmaf(s3, g0.w, e0.w));
        pk.x = pack_bf16(fmaf(s0, g1.x, e1.x), fmaf(s1, g1.y, e1.y));
        pk.y = pack_bf16(fmaf(s2, g1.z, e1.z), fmaf(s3, g1.w, e1.w));
        size_t off = (size_t)(i >> 4) * 4 * 512 + (size_t)(i & 15) * 8 + coff;
        *(uint2*)(qb + off) = pq;
        *(uint2*)(kb + off) = pk;
      }
    }
  } else {
    wave_gemm_t<4,4,4>(xb, DIM_ >> 5, by * 8 + (wave >> 1) * 4,
                       wT, DIM_ >> 5, bx * 8 + (wave & 1) * 4,
                       DIM_ >> 5, acc);
    int b = by >> 4;                               // batch (by*128 / 2048)
    uint16_t* vt = vT + (size_t)b * DV * S_;
    #pragma unroll
    for (int nt = 0; nt < 4; nt++) {
      int n = (bx - 1) * 128 + wcol + nt * 16 + lane16;   // 0..1023
      float bb = bv[n];
      #pragma unroll
      for (int mt = 0; mt < 4; mt++) {
        int j0l = (by & 15) * 128 + wrow + mt * 16 + quad * 4; // local seq
        uint16_t v0 = f32_to_bf16(silu_f(acc[mt][nt][0] + bb));
        uint16_t v1 = f32_to_bf16(silu_f(acc[mt][nt][1] + bb));
        uint16_t v2 = f32_to_bf16(silu_f(acc[mt][nt][2] + bb));
        uint16_t v3 = f32_to_bf16(silu_f(acc[mt][nt][3] + bb));
        size_t off = (size_t)((n >> 4) * 64 + (j0l >> 5)) * 512 +
                     ((j0l >> 3) & 3) * 128 + (n & 15) * 8 + (j0l & 7);
        uint2 pk;
        pk.x = (uint32_t)v0 | ((uint32_t)v1 << 16);
        pk.y = (uint32_t)v2 | ((uint32_t)v3 << 16);
        *(uint2*)(vt + off) = pk;
      }
    }
  }
}

// attn = laplacian(q@k^T/S + bias[i-j]) causal, TILED bf16 per batch.
// 64x64 tile per 128-thread block (2 waves, each 32 i-rows x 64 j-cols),
// exact causal triangle grid (528 tiles/batch). SWAPPED: A = kb rows (j),
// B = qb rows (i) -> lane holds i=lane16 and four consecutive j per
// (mt,quad) -> one packed 8B store each.
__global__ __launch_bounds__(128, 4) void k_gemm_sim(
    const uint16_t* __restrict__ qb, const uint16_t* __restrict__ kb,
    const float* __restrict__ bias_n, uint16_t* __restrict__ attn)
{
  int b = blockIdx.x;                    // 0..527 triangular tile index
  int bt = blockIdx.y;                   // batch
  int it = (int)((sqrtf(8.0f * (float)b + 1.0f) - 1.0f) * 0.5f);
  while ((it + 1) * (it + 2) / 2 <= b) ++it;
  while (it * (it + 1) / 2 > b) --it;
  int jt = b - it * (it + 1) / 2;        // 0..it

  int lane = threadIdx.x & 63;
  int wave = threadIdx.x >> 6;           // 0..1 (i-halves of the 64-row tile)
  int lane16 = lane & 15;
  int quad = lane >> 4;

  f32x4 acc[4][2];
  wave_gemm_t<4,2,2>(kb, 4, bt * 128 + jt * 4,
                     qb, 4, bt * 128 + it * 4 + wave * 2,
                     4, acc);

  uint16_t* ab = attn + (size_t)bt * S_ * S_;
  int ibase = it * 64 + wave * 32;
  int jbase = jt * 64;
  #pragma unroll
  for (int nt = 0; nt < 2; nt++) {
    int i = ibase + nt * 16 + lane16;
    size_t irow = (size_t)(i >> 4) * 64 * 512 + (size_t)(i & 15) * 8;
    #pragma unroll
    for (int mt = 0; mt < 4; mt++) {
      int j0 = jbase + mt * 16 + quad * 4;
      float v[4];
      #pragma unroll
      for (int r = 0; r < 4; r++) {
        int j = j0 + r;
        float aval = 0.0f;
        if (j <= i) {
          float sim = acc[mt][nt][r] * (1.0f / 2048.0f) + bias_n[i - j];
          aval = laplacian_attn(sim);
        }
        v[r] = aval;
      }
      uint2 pk;
      pk.x = pack_bf16(v[0], v[1]);
      pk.y = pack_bf16(v[2], v[3]);
      size_t off = irow + (size_t)(j0 >> 5) * 512 + ((j0 >> 3) & 3) * 128 +
                   (j0 & 7);
      *(uint2*)(ab + off) = pk;
    }
  }
}

// out = attn @ v, fp32 out.  1-D grid 512, swizzled:
//   L%8 selects XCD residue; groups g=(bt,nx) pinned to one XCD so the
//   512KB vT panel stays L2-resident; it descends with L (LPT: heavy
//   causal blocks dispatch first).  SWAPPED operands: A=vT (n rows),
//   B=attn (i rows) -> acc[mt][nt] holds 4 consecutive n -> float4 stores.
__global__ __launch_bounds__(256, 2) void k_gemm_out(
    const uint16_t* __restrict__ attn, const uint16_t* __restrict__ vT,
    float* __restrict__ out)
{
  int L = blockIdx.x;                    // 0..511
  int c = L & 7, m = L >> 3;             // c: XCD residue, m: 0..63
  int g = c + 8 * (m & 3);               // group 0..31 (4 groups per XCD)
  int it = 15 - (m >> 2);                // descending -> LPT
  int bt = g >> 3, nx = g & 7;
  int nkb = 4 * it + 4;                  // causal K bound
  WAVE_PREAMBLE
  f32x4 acc[4][4];
  wave_gemm_t<4,4,4>(vT + (size_t)bt * DV * S_, 64, nx * 8 + (wave & 1) * 4,
                     attn + (size_t)bt * S_ * S_, 64, it * 8 + (wave >> 1) * 4,
                     nkb, acc);
  // acc[mt][nt][r]: n = nx*128 + wcol + mt*16 + quad*4 + r
  //                 i = it*128 + wrow + nt*16 + lane16
  float* ob = out + ((size_t)bt * S_ + it * 128 + wrow) * DV + nx * 128 + wcol;
  #pragma unroll
  for (int nt = 0; nt < 4; nt++) {
    int i = nt * 16 + lane16;
    #pragma unroll
    for (int mt = 0; mt < 4; mt++) {
      int n = mt * 16 + quad * 4;
      *(float4*)(ob + (size_t)i * DV + n) = *(float4*)&acc[mt][nt];
    }
  }
}

// ---------------------------------------------------------------------------

extern "C" void kernel_launch(void* const* d_in, const int* in_sizes, int n_in,
                              void* d_out, int out_size, void* d_ws, size_t ws_size,
                              hipStream_t stream)
{
  const float* x     = (const float*)d_in[0];
  const float* wqk   = (const float*)d_in[1];
  const float* bqk   = (const float*)d_in[2];
  const float* gamma = (const float*)d_in[3];
  const float* beta  = (const float*)d_in[4];
  const float* wv    = (const float*)d_in[5];
  const float* bv    = (const float*)d_in[6];
  const float* rel   = (const float*)d_in[7];
  float* out = (float*)d_out;

  char* ws = (char*)d_ws;
  size_t off = 0;
  uint16_t* xb     = (uint16_t*)(ws + off); off += (size_t)B_ * S_ * DIM_ * 2;  // 16 MB
  uint16_t* wT     = (uint16_t*)(ws + off); off += (size_t)NQV * DIM_ * 2;      // 2.25 MB
  uint16_t* qb     = (uint16_t*)(ws + off); off += (size_t)B_ * S_ * DQK * 2;   // 2 MB
  uint16_t* kb     = (uint16_t*)(ws + off); off += (size_t)B_ * S_ * DQK * 2;   // 2 MB
  uint16_t* vT     = (uint16_t*)(ws + off); off += (size_t)B_ * DV * S_ * 2;    // 16 MB
  uint16_t* attn   = (uint16_t*)(ws + off); off += (size_t)B_ * S_ * S_ * 2;    // 32 MB
  float*    bias_n = (float*)(ws + off);    off += (size_t)S_ * 4;              // 8 KB

  k_prep_x<<<dim3(B_ * S_ * DIM_ / 8 / 256), dim3(256), 0, stream>>>(x, xb);
  k_prep_w<<<dim3(NQV * DIM_ / 8 / 256), dim3(256), 0, stream>>>(wqk, wv, wT);
  k_bias<<<dim3(S_ / 256), dim3(256), 0, stream>>>(rel, bias_n);

  k_gemm_qkv<<<dim3(NQV / 128, B_ * S_ / 128), dim3(256), 0, stream>>>(
      xb, wT, bqk, gamma, beta, bv, qb, kb, vT);
  k_gemm_sim<<<dim3(528, B_), dim3(128), 0, stream>>>(
      qb, kb, bias_n, attn);
  k_gemm_out<<<dim3(512), dim3(256), 0, stream>>>(
      attn, vT, out);
}

// Round 5
// 172.861 us; speedup vs baseline: 1.3081x; 1.1035x over previous
//
#include <hip/hip_runtime.h>
#include <stdint.h>

// ---------------------------------------------------------------------------
// SingleHeadedAttention (Mega-style, laplacian attn fn, causal, T5 rel bias)
// B=4, S=2048, DIM=1024, DQK=128, DV=1024.  fp32 in/out, bf16 MFMA internals.
// R13: top-5 now all harness fills (41.6us) -> kernels each <=41.6, counters
//   masked. Delta algebra suggests R12's qkv (DEPTH=4,(256,2)) may have
//   regressed ~10us (VGPR 76->~210, waves 3->2/SIMD). This round:
//   - qkv: A/B revert to DEPTH=2 + (256,3) (known-good R11 config).
//   - qkv: 1-D grid, all 9 bx of a by pinned to one XCD (xb panel fetched by
//     1 XCD instead of up to 8; per-XCD set ~4.25MB ~= L2).
//   - out: XCD c serves ONE bt (c>>1); 4 nx-blocks at same it share one
//     <=512KB attn panel in L2 (R12 put all 4 bt triangles on every XCD).
//   - prep_x/prep_w/bias fused into one kernel (3 launches -> 1).
// R12: out: DEPTH=4 pipeline, LPT it-descending, swapped operands (float4
//   epilogue stores). R11: sim TLP fix (32x64 wave tiles, 128-thr blocks,
//   exact triangle grid, (128,4)). R10: branchless erf; swapped QK^T.
//   TILED: element (row,k) of [R][K] at
//     ((row>>4)*(K>>5) + (k>>5))*512 + ((k>>3)&3)*128 + (row&15)*8 + (k&7).
//   Lane l's MFMA fragment of a 16x32 block = 16 contiguous bytes at
//   base + l*16 -> one coalesced global_load_dwordx4 per fragment. No LDS,
//   no barriers, no DMA in the GEMMs.
// ---------------------------------------------------------------------------

#define B_   4
#define S_   2048
#define DIM_ 1024
#define DQK  128
#define DV   1024
#define NQV  1152

typedef __attribute__((ext_vector_type(8))) short short8;   // 8 bf16
typedef __attribute__((ext_vector_type(4))) float f32x4;    // MFMA C/D

__device__ __forceinline__ uint16_t f32_to_bf16(float f) {
  uint32_t u = __float_as_uint(f);
  u += 0x7FFFu + ((u >> 16) & 1u);          // round-to-nearest-even
  return (uint16_t)(u >> 16);
}

__device__ __forceinline__ uint32_t pack_bf16(float a, float b) {
  return (uint32_t)f32_to_bf16(a) | ((uint32_t)f32_to_bf16(b) << 16);
}

__device__ __forceinline__ float silu_f(float x) {
  // x * sigmoid(x), native exp + v_rcp (bf16 output tolerates ~1e-6 rel err)
  return x * __builtin_amdgcn_rcpf(1.0f + __expf(-x));
}

// 0.5*(1+erf((x-mu)/(std*sqrt2))), mu=sqrt(0.5), std=sqrt(pi/4).
// Branchless Abramowitz-Stegun 7.1.26 erf approx, |eps| <= 1.5e-7.
__device__ __forceinline__ float laplacian_attn(float x) {
  float z  = (x - 0.70710678118654752f) * 0.79788456080286536f;
  float az = fabsf(z);
  float t  = __builtin_amdgcn_rcpf(fmaf(0.3275911f, az, 1.0f));
  float w  = fmaf(1.061405429f, t, -1.453152027f);
  w = fmaf(w, t, 1.421413741f);
  w = fmaf(w, t, -0.284496736f);
  w = fmaf(w, t, 0.254829592f);
  float P  = w * t;
  float E  = __expf(-z * z);
  float ea = fmaf(-P, E, 1.0f);            // erf(|z|)
  float er = copysignf(ea, z);
  return fmaf(0.5f, er, 0.5f);
}

// ---- wave-private MTxNT (16-row units) GEMM on TILED operands -------------
// A tiled [RA][K] row-blocks rbA..+MT-1, Bt tiled [RB][K] rbB..+NT-1.
// KBa/KBb = K>>5. DEPTH=2: nkb even >=2. DEPTH=4: nkb multiple of 4 >=4.
// Fragments global->VGPR, contiguous 16B/lane.
template <int MT, int NT, int DEPTH>
__device__ __forceinline__ void wave_gemm_t(
    const uint16_t* __restrict__ A, int KBa, int rbA,
    const uint16_t* __restrict__ Bt, int KBb, int rbB,
    int nkb, f32x4 acc[MT][NT])
{
  const int lane = threadIdx.x & 63;

  const uint16_t* pa[MT];
  const uint16_t* pb[NT];
  #pragma unroll
  for (int mt = 0; mt < MT; mt++)
    pa[mt] = A + (size_t)(rbA + mt) * KBa * 512 + lane * 8;
  #pragma unroll
  for (int nt = 0; nt < NT; nt++)
    pb[nt] = Bt + (size_t)(rbB + nt) * KBb * 512 + lane * 8;

  #pragma unroll
  for (int mt = 0; mt < MT; mt++)
    #pragma unroll
    for (int nt = 0; nt < NT; nt++) {
      f32x4 z = {0.0f, 0.0f, 0.0f, 0.0f};
      acc[mt][nt] = z;
    }

  short8 fa0[MT], fb0[NT], fa1[MT], fb1[NT];

  auto loads = [&](short8 fa[MT], short8 fb[NT], int kb) {
    #pragma unroll
    for (int mt = 0; mt < MT; mt++)
      fa[mt] = *(const short8*)(pa[mt] + (size_t)kb * 512);
    #pragma unroll
    for (int nt = 0; nt < NT; nt++)
      fb[nt] = *(const short8*)(pb[nt] + (size_t)kb * 512);
  };
  auto mfmas = [&](short8 fa[MT], short8 fb[NT]) {
    #pragma unroll
    for (int mt = 0; mt < MT; mt++)
      #pragma unroll
      for (int nt = 0; nt < NT; nt++)
        acc[mt][nt] = __builtin_amdgcn_mfma_f32_16x16x32_bf16(
            fa[mt], fb[nt], acc[mt][nt], 0, 0, 0);
  };

  if constexpr (DEPTH == 2) {
    loads(fa0, fb0, 0);
    loads(fa1, fb1, 1);
    for (int kb = 2; kb < nkb; kb += 2) {
      mfmas(fa0, fb0);
      loads(fa0, fb0, kb);
      mfmas(fa1, fb1);
      loads(fa1, fb1, kb + 1);
    }
    mfmas(fa0, fb0);
    mfmas(fa1, fb1);
  } else {
    short8 fa2[MT], fb2[NT], fa3[MT], fb3[NT];
    loads(fa0, fb0, 0);
    loads(fa1, fb1, 1);
    loads(fa2, fb2, 2);
    loads(fa3, fb3, 3);
    for (int kb = 4; kb < nkb; kb += 4) {
      mfmas(fa0, fb0);
      loads(fa0, fb0, kb);
      mfmas(fa1, fb1);
      loads(fa1, fb1, kb + 1);
      mfmas(fa2, fb2);
      loads(fa2, fb2, kb + 2);
      mfmas(fa3, fb3);
      loads(fa3, fb3, kb + 3);
    }
    mfmas(fa0, fb0);
    mfmas(fa1, fb1);
    mfmas(fa2, fb2);
    mfmas(fa3, fb3);
  }
}

// 256-thread block = 4 independent waves over a 128x128 tile.
// wave w: rows +(w>>1)*64 (row-blocks +(w>>1)*4), cols +(w&1)*64.
#define WAVE_PREAMBLE                                  \
  int lane = threadIdx.x & 63;                         \
  int wave = threadIdx.x >> 6;                         \
  int lane16 = lane & 15;                              \
  int quad = lane >> 4;                                \
  int wrow = (wave >> 1) * 64;                         \
  int wcol = (wave & 1) * 64;

// ---- fused prep kernel -----------------------------------------------------
// blocks 0..4095: x fp32 [8192][1024] -> xb TILED bf16.
// blocks 4096..4671: wqk/wv -> wT TILED bf16 (rows n=0..1151).
// block 4672: bias_n[n] = rel_bias[bucket(n)] * sqrt(DQK).
__global__ __launch_bounds__(256) void k_prep(
    const float* __restrict__ x, const float* __restrict__ wqk,
    const float* __restrict__ wv, const float* __restrict__ rel,
    uint16_t* __restrict__ xb, uint16_t* __restrict__ wT,
    float* __restrict__ bias_n)
{
  int blk = blockIdx.x;
  if (blk < 4096) {
    int t = blk * 256 + threadIdx.x;           // 0 .. 8192*128-1
    int i16 = t & 15, oct = (t >> 4) & 3, kb = (t >> 6) & 31, ib = t >> 11;
    const float* src = x + (size_t)(ib * 16 + i16) * DIM_ + kb * 32 + oct * 8;
    float4 a = *(const float4*)src;
    float4 b = *(const float4*)(src + 4);
    short8 o;
    o[0] = f32_to_bf16(a.x); o[1] = f32_to_bf16(a.y);
    o[2] = f32_to_bf16(a.z); o[3] = f32_to_bf16(a.w);
    o[4] = f32_to_bf16(b.x); o[5] = f32_to_bf16(b.y);
    o[6] = f32_to_bf16(b.z); o[7] = f32_to_bf16(b.w);
    *(short8*)(xb + (size_t)t * 8) = o;
  } else if (blk < 4672) {
    int t = (blk - 4096) * 256 + threadIdx.x;  // 0 .. 1152*128-1
    int n16 = t & 15, oct = (t >> 4) & 3, kb = (t >> 6) & 31, nb = t >> 11;
    int n = nb * 16 + n16;
    int k0 = kb * 32 + oct * 8;
    short8 o;
    if (n < DQK) {
      #pragma unroll
      for (int j = 0; j < 8; j++)
        o[j] = f32_to_bf16(wqk[(size_t)(k0 + j) * DQK + n]);
    } else {
      int nn = n - DQK;
      #pragma unroll
      for (int j = 0; j < 8; j++)
        o[j] = f32_to_bf16(wv[(size_t)(k0 + j) * DV + nn]);
    }
    *(short8*)(wT + (size_t)t * 8) = o;
  } else {
    for (int n = threadIdx.x; n < S_; n += 256) {
      int bucket;
      if (n < 16) {
        bucket = n;
      } else {
        float tt = logf((float)n * 0.0625f) / 2.0794415416798357f * 16.0f;
        int vl = 16 + (int)tt;
        bucket = vl < 31 ? vl : 31;
      }
      bias_n[n] = rel[bucket] * 11.313708498984761f;
    }
  }
}

// ---- GEMM kernels ----------------------------------------------------------

// fused projections. 1-D grid 576: XCD c = L&7 owns by in {c, c+8, .., c+56}
// (all 9 bx of a by on one XCD -> xb panel fetched by one L2; per-XCD set
// 8 xb panels (2MB) + wT (2.25MB) ~= 4MB L2).
// bx==0 -> q/k epilogue (SWAPPED operands: lane holds 4 consecutive dqk cols
// -> packed 8B stores); bx>=1 -> v -> vT TILED.
__global__ __launch_bounds__(256, 3) void k_gemm_qkv(
    const uint16_t* __restrict__ xb, const uint16_t* __restrict__ wT,
    const float* __restrict__ bqk, const float* __restrict__ gamma,
    const float* __restrict__ beta, const float* __restrict__ bv,
    uint16_t* __restrict__ qb, uint16_t* __restrict__ kb,
    uint16_t* __restrict__ vT)
{
  int L = blockIdx.x;                    // 0..575
  int c = L & 7;
  int idx = L >> 3;                      // 0..71
  int by = c + 8 * (idx / 9);
  int bx = idx % 9;
  WAVE_PREAMBLE
  f32x4 acc[4][4];

  if (bx == 0) {
    // A = wT rows (dqk cols c), B = xb rows (seq i).  acc[mt][nt]:
    // c = (wave>>1)*64 + mt*16 + quad*4 + r,  i = by*128 + (wave&1)*64 + nt*16 + lane16
    wave_gemm_t<4,4,2>(wT, DIM_ >> 5, (wave >> 1) * 4,
                       xb, DIM_ >> 5, by * 8 + (wave & 1) * 4,
                       DIM_ >> 5, acc);
    int ibase = by * 128 + (wave & 1) * 64;
    int cbase = (wave >> 1) * 64;
    #pragma unroll
    for (int mt = 0; mt < 4; mt++) {
      int c0 = cbase + mt * 16 + quad * 4;
      float4 bb = *(const float4*)(bqk + c0);
      float4 g0 = *(const float4*)(gamma + c0);
      float4 g1 = *(const float4*)(gamma + DQK + c0);
      float4 e0 = *(const float4*)(beta + c0);
      float4 e1 = *(const float4*)(beta + DQK + c0);
      size_t coff = (size_t)(c0 >> 5) * 512 + ((c0 >> 3) & 3) * 128 + (c0 & 7);
      #pragma unroll
      for (int nt = 0; nt < 4; nt++) {
        int i = ibase + nt * 16 + lane16;
        float s0 = silu_f(acc[mt][nt][0] + bb.x);
        float s1 = silu_f(acc[mt][nt][1] + bb.y);
        float s2 = silu_f(acc[mt][nt][2] + bb.z);
        float s3 = silu_f(acc[mt][nt][3] + bb.w);
        uint2 pq, pk;
        pq.x = pack_bf16(fmaf(s0, g0.x, e0.x), fmaf(s1, g0.y, e0.y));
        pq.y = pack_bf16(fmaf(s2, g0.z, e0.z), fmaf(s3, g0.w, e0.w));
        pk.x = pack_bf16(fmaf(s0, g1.x, e1.x), fmaf(s1, g1.y, e1.y));
        pk.y = pack_bf16(fmaf(s2, g1.z, e1.z), fmaf(s3, g1.w, e1.w));
        size_t off = (size_t)(i >> 4) * 4 * 512 + (size_t)(i & 15) * 8 + coff;
        *(uint2*)(qb + off) = pq;
        *(uint2*)(kb + off) = pk;
      }
    }
  } else {
    wave_gemm_t<4,4,2>(xb, DIM_ >> 5, by * 8 + (wave >> 1) * 4,
                       wT, DIM_ >> 5, bx * 8 + (wave & 1) * 4,
                       DIM_ >> 5, acc);
    int b = by >> 4;                               // batch (by*128 / 2048)
    uint16_t* vt = vT + (size_t)b * DV * S_;
    #pragma unroll
    for (int nt = 0; nt < 4; nt++) {
      int n = (bx - 1) * 128 + wcol + nt * 16 + lane16;   // 0..1023
      float bb = bv[n];
      #pragma unroll
      for (int mt = 0; mt < 4; mt++) {
        int j0l = (by & 15) * 128 + wrow + mt * 16 + quad * 4; // local seq
        uint16_t v0 = f32_to_bf16(silu_f(acc[mt][nt][0] + bb));
        uint16_t v1 = f32_to_bf16(silu_f(acc[mt][nt][1] + bb));
        uint16_t v2 = f32_to_bf16(silu_f(acc[mt][nt][2] + bb));
        uint16_t v3 = f32_to_bf16(silu_f(acc[mt][nt][3] + bb));
        size_t off = (size_t)((n >> 4) * 64 + (j0l >> 5)) * 512 +
                     ((j0l >> 3) & 3) * 128 + (n & 15) * 8 + (j0l & 7);
        uint2 pk;
        pk.x = (uint32_t)v0 | ((uint32_t)v1 << 16);
        pk.y = (uint32_t)v2 | ((uint32_t)v3 << 16);
        *(uint2*)(vt + off) = pk;
      }
    }
  }
}

// attn = laplacian(q@k^T/S + bias[i-j]) causal, TILED bf16 per batch.
// 64x64 tile per 128-thread block (2 waves, each 32 i-rows x 64 j-cols),
// exact causal triangle grid (528 tiles/batch). SWAPPED: A = kb rows (j),
// B = qb rows (i) -> lane holds i=lane16 and four consecutive j per
// (mt,quad) -> one packed 8B store each.
__global__ __launch_bounds__(128, 4) void k_gemm_sim(
    const uint16_t* __restrict__ qb, const uint16_t* __restrict__ kb,
    const float* __restrict__ bias_n, uint16_t* __restrict__ attn)
{
  int b = blockIdx.x;                    // 0..527 triangular tile index
  int bt = blockIdx.y;                   // batch
  int it = (int)((sqrtf(8.0f * (float)b + 1.0f) - 1.0f) * 0.5f);
  while ((it + 1) * (it + 2) / 2 <= b) ++it;
  while (it * (it + 1) / 2 > b) --it;
  int jt = b - it * (it + 1) / 2;        // 0..it

  int lane = threadIdx.x & 63;
  int wave = threadIdx.x >> 6;           // 0..1 (i-halves of the 64-row tile)
  int lane16 = lane & 15;
  int quad = lane >> 4;

  f32x4 acc[4][2];
  wave_gemm_t<4,2,2>(kb, 4, bt * 128 + jt * 4,
                     qb, 4, bt * 128 + it * 4 + wave * 2,
                     4, acc);

  uint16_t* ab = attn + (size_t)bt * S_ * S_;
  int ibase = it * 64 + wave * 32;
  int jbase = jt * 64;
  #pragma unroll
  for (int nt = 0; nt < 2; nt++) {
    int i = ibase + nt * 16 + lane16;
    size_t irow = (size_t)(i >> 4) * 64 * 512 + (size_t)(i & 15) * 8;
    #pragma unroll
    for (int mt = 0; mt < 4; mt++) {
      int j0 = jbase + mt * 16 + quad * 4;
      float v[4];
      #pragma unroll
      for (int r = 0; r < 4; r++) {
        int j = j0 + r;
        float aval = 0.0f;
        if (j <= i) {
          float sim = acc[mt][nt][r] * (1.0f / 2048.0f) + bias_n[i - j];
          aval = laplacian_attn(sim);
        }
        v[r] = aval;
      }
      uint2 pk;
      pk.x = pack_bf16(v[0], v[1]);
      pk.y = pack_bf16(v[2], v[3]);
      size_t off = irow + (size_t)(j0 >> 5) * 512 + ((j0 >> 3) & 3) * 128 +
                   (j0 & 7);
      *(uint2*)(ab + off) = pk;
    }
  }
}

// out = attn @ v, fp32 out.  1-D grid 512: XCD c = L&7 serves ONE bt (c>>1);
// nx = (c&1)*4 + (m&3); it = 15-(m>>2) (descending -> LPT). The 4 nx-blocks
// at the same it on an XCD share one <=512KB attn panel in L2.  SWAPPED
// operands: A=vT (n rows), B=attn (i rows) -> acc holds 4 consecutive n ->
// float4 epilogue stores.
__global__ __launch_bounds__(256, 2) void k_gemm_out(
    const uint16_t* __restrict__ attn, const uint16_t* __restrict__ vT,
    float* __restrict__ out)
{
  int L = blockIdx.x;                    // 0..511
  int c = L & 7, m = L >> 3;             // c: XCD residue, m: 0..63
  int bt = c >> 1;                       // one batch per XCD pair-residue
  int nx = (c & 1) * 4 + (m & 3);        // 0..7
  int it = 15 - (m >> 2);                // descending -> LPT
  int nkb = 4 * it + 4;                  // causal K bound
  WAVE_PREAMBLE
  f32x4 acc[4][4];
  wave_gemm_t<4,4,4>(vT + (size_t)bt * DV * S_, 64, nx * 8 + (wave & 1) * 4,
                     attn + (size_t)bt * S_ * S_, 64, it * 8 + (wave >> 1) * 4,
                     nkb, acc);
  // acc[mt][nt][r]: n = nx*128 + wcol + mt*16 + quad*4 + r
  //                 i = it*128 + wrow + nt*16 + lane16
  float* ob = out + ((size_t)bt * S_ + it * 128 + wrow) * DV + nx * 128 + wcol;
  #pragma unroll
  for (int nt = 0; nt < 4; nt++) {
    int i = nt * 16 + lane16;
    #pragma unroll
    for (int mt = 0; mt < 4; mt++) {
      int n = mt * 16 + quad * 4;
      *(float4*)(ob + (size_t)i * DV + n) = *(float4*)&acc[mt][nt];
    }
  }
}

// ---------------------------------------------------------------------------

extern "C" void kernel_launch(void* const* d_in, const int* in_sizes, int n_in,
                              void* d_out, int out_size, void* d_ws, size_t ws_size,
                              hipStream_t stream)
{
  const float* x     = (const float*)d_in[0];
  const float* wqk   = (const float*)d_in[1];
  const float* bqk   = (const float*)d_in[2];
  const float* gamma = (const float*)d_in[3];
  const float* beta  = (const float*)d_in[4];
  const float* wv    = (const float*)d_in[5];
  const float* bv    = (const float*)d_in[6];
  const float* rel   = (const float*)d_in[7];
  float* out = (float*)d_out;

  char* ws = (char*)d_ws;
  size_t off = 0;
  uint16_t* xb     = (uint16_t*)(ws + off); off += (size_t)B_ * S_ * DIM_ * 2;  // 16 MB
  uint16_t* wT     = (uint16_t*)(ws + off); off += (size_t)NQV * DIM_ * 2;      // 2.25 MB
  uint16_t* qb     = (uint16_t*)(ws + off); off += (size_t)B_ * S_ * DQK * 2;   // 2 MB
  uint16_t* kb     = (uint16_t*)(ws + off); off += (size_t)B_ * S_ * DQK * 2;   // 2 MB
  uint16_t* vT     = (uint16_t*)(ws + off); off += (size_t)B_ * DV * S_ * 2;    // 16 MB
  uint16_t* attn   = (uint16_t*)(ws + off); off += (size_t)B_ * S_ * S_ * 2;    // 32 MB
  float*    bias_n = (float*)(ws + off);    off += (size_t)S_ * 4;              // 8 KB

  k_prep<<<dim3(4673), dim3(256), 0, stream>>>(x, wqk, wv, rel, xb, wT, bias_n);

  k_gemm_qkv<<<dim3(576), dim3(256), 0, stream>>>(
      xb, wT, bqk, gamma, beta, bv, qb, kb, vT);
  k_gemm_sim<<<dim3(528, B_), dim3(128), 0, stream>>>(
      qb, kb, bias_n, attn);
  k_gemm_out<<<dim3(512), dim3(256), 0, stream>>>(
      attn, vT, out);
}

// Round 6
// 171.014 us; speedup vs baseline: 1.3222x; 1.0108x over previous
//
#include <hip/hip_runtime.h>
#include <stdint.h>

// ---------------------------------------------------------------------------
// SingleHeadedAttention (Mega-style, laplacian attn fn, causal, T5 rel bias)
// B=4, S=2048, DIM=1024, DQK=128, DV=1024.  fp32 in/out, bf16 MFMA internals.
// R14: qkv + out rewritten as LDS-staged 128x128-tile GEMMs (m97 structure):
//   single-buffered 2-barrier K-loop, BK=64 (2 k-blocks/step), staging via
//   __builtin_amdgcn_global_load_lds width=16 (TILED layout: each
//   (row-block,k-block) unit = 1024B contiguous = one wave-wide DMA).
//   Eliminates the reg-direct design's 2x wave-pair L2 redundancy and the
//   per-fragment vmcnt round-trips. Fragment values from LDS are identical
//   to R13's global reads -> epilogues/indexing unchanged. sim/prep as R13.
// R13: qkv DEPTH2+(256,3) revert; XCD-pinned grids (qkv: 9 bx of a by on one
//   XCD; out: one bt per XCD-pair, LPT it-desc); fused prep.
// R12: out swapped operands (float4 stores). R11: sim TLP fix (32x64 tiles,
//   128-thr blocks, triangle grid). R10: branchless erf; swapped QK^T.
//   TILED: element (row,k) of [R][K] at
//     ((row>>4)*(K>>5) + (k>>5))*512 + ((k>>3)&3)*128 + (row&15)*8 + (k&7).
// ---------------------------------------------------------------------------

#define B_   4
#define S_   2048
#define DIM_ 1024
#define DQK  128
#define DV   1024
#define NQV  1152

typedef __attribute__((ext_vector_type(8))) short short8;   // 8 bf16
typedef __attribute__((ext_vector_type(4))) float f32x4;    // MFMA C/D

__device__ __forceinline__ uint16_t f32_to_bf16(float f) {
  uint32_t u = __float_as_uint(f);
  u += 0x7FFFu + ((u >> 16) & 1u);          // round-to-nearest-even
  return (uint16_t)(u >> 16);
}

__device__ __forceinline__ uint32_t pack_bf16(float a, float b) {
  return (uint32_t)f32_to_bf16(a) | ((uint32_t)f32_to_bf16(b) << 16);
}

__device__ __forceinline__ float silu_f(float x) {
  return x * __builtin_amdgcn_rcpf(1.0f + __expf(-x));
}

// 0.5*(1+erf((x-mu)/(std*sqrt2))), mu=sqrt(0.5), std=sqrt(pi/4).
// Branchless Abramowitz-Stegun 7.1.26 erf approx, |eps| <= 1.5e-7.
__device__ __forceinline__ float laplacian_attn(float x) {
  float z  = (x - 0.70710678118654752f) * 0.79788456080286536f;
  float az = fabsf(z);
  float t  = __builtin_amdgcn_rcpf(fmaf(0.3275911f, az, 1.0f));
  float w  = fmaf(1.061405429f, t, -1.453152027f);
  w = fmaf(w, t, 1.421413741f);
  w = fmaf(w, t, -0.284496736f);
  w = fmaf(w, t, 0.254829592f);
  float P  = w * t;
  float E  = __expf(-z * z);
  float ea = fmaf(-P, E, 1.0f);            // erf(|z|)
  float er = copysignf(ea, z);
  return fmaf(0.5f, er, 0.5f);
}

// global->LDS DMA, 16B per lane: lane l of the wave writes lds_base + l*16
// from gsrc + l*16 (gsrc per-lane, lds base wave-uniform).
__device__ __forceinline__ void gload16(const uint16_t* g, uint16_t* l) {
  __builtin_amdgcn_global_load_lds(
      (const __attribute__((address_space(1))) void*)g,
      (__attribute__((address_space(3))) void*)l, 16, 0, 0);
}

// ---- wave-private MTxNT (16-row units) GEMM on TILED operands -------------
// (reg-direct version; still used by k_gemm_sim where K is tiny)
template <int MT, int NT, int DEPTH>
__device__ __forceinline__ void wave_gemm_t(
    const uint16_t* __restrict__ A, int KBa, int rbA,
    const uint16_t* __restrict__ Bt, int KBb, int rbB,
    int nkb, f32x4 acc[MT][NT])
{
  const int lane = threadIdx.x & 63;

  const uint16_t* pa[MT];
  const uint16_t* pb[NT];
  #pragma unroll
  for (int mt = 0; mt < MT; mt++)
    pa[mt] = A + (size_t)(rbA + mt) * KBa * 512 + lane * 8;
  #pragma unroll
  for (int nt = 0; nt < NT; nt++)
    pb[nt] = Bt + (size_t)(rbB + nt) * KBb * 512 + lane * 8;

  #pragma unroll
  for (int mt = 0; mt < MT; mt++)
    #pragma unroll
    for (int nt = 0; nt < NT; nt++) {
      f32x4 z = {0.0f, 0.0f, 0.0f, 0.0f};
      acc[mt][nt] = z;
    }

  short8 fa0[MT], fb0[NT], fa1[MT], fb1[NT];

  auto loads = [&](short8 fa[MT], short8 fb[NT], int kb) {
    #pragma unroll
    for (int mt = 0; mt < MT; mt++)
      fa[mt] = *(const short8*)(pa[mt] + (size_t)kb * 512);
    #pragma unroll
    for (int nt = 0; nt < NT; nt++)
      fb[nt] = *(const short8*)(pb[nt] + (size_t)kb * 512);
  };
  auto mfmas = [&](short8 fa[MT], short8 fb[NT]) {
    #pragma unroll
    for (int mt = 0; mt < MT; mt++)
      #pragma unroll
      for (int nt = 0; nt < NT; nt++)
        acc[mt][nt] = __builtin_amdgcn_mfma_f32_16x16x32_bf16(
            fa[mt], fb[nt], acc[mt][nt], 0, 0, 0);
  };

  loads(fa0, fb0, 0);
  loads(fa1, fb1, 1);
  for (int kb = 2; kb < nkb; kb += 2) {
    mfmas(fa0, fb0);
    loads(fa0, fb0, kb);
    mfmas(fa1, fb1);
    loads(fa1, fb1, kb + 1);
  }
  mfmas(fa0, fb0);
  mfmas(fa1, fb1);
}

// 256-thread block = 4 waves over a 128x128 tile.
#define WAVE_PREAMBLE                                  \
  int lane = threadIdx.x & 63;                         \
  int wave = threadIdx.x >> 6;                         \
  int lane16 = lane & 15;                              \
  int quad = lane >> 4;                                \
  int wrow = (wave >> 1) * 64;                         \
  int wcol = (wave & 1) * 64;

// ---- fused prep kernel -----------------------------------------------------
__global__ __launch_bounds__(256) void k_prep(
    const float* __restrict__ x, const float* __restrict__ wqk,
    const float* __restrict__ wv, const float* __restrict__ rel,
    uint16_t* __restrict__ xb, uint16_t* __restrict__ wT,
    float* __restrict__ bias_n)
{
  int blk = blockIdx.x;
  if (blk < 4096) {
    int t = blk * 256 + threadIdx.x;           // 0 .. 8192*128-1
    int i16 = t & 15, oct = (t >> 4) & 3, kb = (t >> 6) & 31, ib = t >> 11;
    const float* src = x + (size_t)(ib * 16 + i16) * DIM_ + kb * 32 + oct * 8;
    float4 a = *(const float4*)src;
    float4 b = *(const float4*)(src + 4);
    short8 o;
    o[0] = f32_to_bf16(a.x); o[1] = f32_to_bf16(a.y);
    o[2] = f32_to_bf16(a.z); o[3] = f32_to_bf16(a.w);
    o[4] = f32_to_bf16(b.x); o[5] = f32_to_bf16(b.y);
    o[6] = f32_to_bf16(b.z); o[7] = f32_to_bf16(b.w);
    *(short8*)(xb + (size_t)t * 8) = o;
  } else if (blk < 4672) {
    int t = (blk - 4096) * 256 + threadIdx.x;  // 0 .. 1152*128-1
    int n16 = t & 15, oct = (t >> 4) & 3, kb = (t >> 6) & 31, nb = t >> 11;
    int n = nb * 16 + n16;
    int k0 = kb * 32 + oct * 8;
    short8 o;
    if (n < DQK) {
      #pragma unroll
      for (int j = 0; j < 8; j++)
        o[j] = f32_to_bf16(wqk[(size_t)(k0 + j) * DQK + n]);
    } else {
      int nn = n - DQK;
      #pragma unroll
      for (int j = 0; j < 8; j++)
        o[j] = f32_to_bf16(wv[(size_t)(k0 + j) * DV + nn]);
    }
    *(short8*)(wT + (size_t)t * 8) = o;
  } else {
    for (int n = threadIdx.x; n < S_; n += 256) {
      int bucket;
      if (n < 16) {
        bucket = n;
      } else {
        float tt = logf((float)n * 0.0625f) / 2.0794415416798357f * 16.0f;
        int vl = 16 + (int)tt;
        bucket = vl < 31 ? vl : 31;
      }
      bias_n[n] = rel[bucket] * 11.313708498984761f;
    }
  }
}

// ---- GEMM kernels ----------------------------------------------------------

// fused projections, LDS-staged. 1-D grid 576, XCD-pinned as R13.
// Panels: 8 row-blocks x 2 k-blocks staged per step (16KB A + 16KB B LDS).
// Wave w stages rbu = (w&1)*4..+3 of panel (w>>1 ? B : A).
// bx==0: A=wT (dqk cols), B=xb rows -> packed q/k stores.
// bx>=1: A=xb rows, B=wT v-cols -> vT TILED stores.
__global__ __launch_bounds__(256, 3) void k_gemm_qkv(
    const uint16_t* __restrict__ xb, const uint16_t* __restrict__ wT,
    const float* __restrict__ bqk, const float* __restrict__ gamma,
    const float* __restrict__ beta, const float* __restrict__ bv,
    uint16_t* __restrict__ qb, uint16_t* __restrict__ kb,
    uint16_t* __restrict__ vT)
{
  int L = blockIdx.x;                    // 0..575
  int c = L & 7;
  int idx = L >> 3;                      // 0..71
  int by = c + 8 * (idx / 9);
  int bx = idx % 9;
  WAVE_PREAMBLE

  __shared__ uint16_t sA[8 * 2 * 512];   // [rbu][kk][512]
  __shared__ uint16_t sB[8 * 2 * 512];

  const uint16_t *Ab, *Bb;
  if (bx == 0) { Ab = wT;                              Bb = xb + (size_t)by * 8 * 32 * 512; }
  else         { Ab = xb + (size_t)by * 8 * 32 * 512;  Bb = wT + (size_t)bx * 8 * 32 * 512; }

  const uint16_t* gp = (wave >> 1) ? Bb : Ab;
  uint16_t*       sp = (wave >> 1) ? sB : sA;
  int rb0 = (wave & 1) * 4;

  f32x4 acc[4][4];
  #pragma unroll
  for (int mt = 0; mt < 4; mt++)
    #pragma unroll
    for (int nt = 0; nt < 4; nt++) {
      f32x4 z = {0.0f, 0.0f, 0.0f, 0.0f};
      acc[mt][nt] = z;
    }

  for (int kbi = 0; kbi < 32; kbi += 2) {
    #pragma unroll
    for (int uu = 0; uu < 8; uu++) {
      int rbu = rb0 + (uu >> 1), kk = uu & 1;
      gload16(gp + ((size_t)rbu * 32 + kbi + kk) * 512 + lane * 8,
              sp + (rbu * 2 + kk) * 512);
    }
    __syncthreads();
    #pragma unroll
    for (int kk = 0; kk < 2; kk++) {
      short8 fa[4], fb[4];
      #pragma unroll
      for (int mt = 0; mt < 4; mt++)
        fa[mt] = *(const short8*)(sA + (((wave >> 1) * 4 + mt) * 2 + kk) * 512 + lane * 8);
      #pragma unroll
      for (int nt = 0; nt < 4; nt++)
        fb[nt] = *(const short8*)(sB + (((wave & 1) * 4 + nt) * 2 + kk) * 512 + lane * 8);
      #pragma unroll
      for (int mt = 0; mt < 4; mt++)
        #pragma unroll
        for (int nt = 0; nt < 4; nt++)
          acc[mt][nt] = __builtin_amdgcn_mfma_f32_16x16x32_bf16(
              fa[mt], fb[nt], acc[mt][nt], 0, 0, 0);
    }
    __syncthreads();
  }

  if (bx == 0) {
    int ibase = by * 128 + (wave & 1) * 64;
    int cbase = (wave >> 1) * 64;
    #pragma unroll
    for (int mt = 0; mt < 4; mt++) {
      int c0 = cbase + mt * 16 + quad * 4;
      float4 bb = *(const float4*)(bqk + c0);
      float4 g0 = *(const float4*)(gamma + c0);
      float4 g1 = *(const float4*)(gamma + DQK + c0);
      float4 e0 = *(const float4*)(beta + c0);
      float4 e1 = *(const float4*)(beta + DQK + c0);
      size_t coff = (size_t)(c0 >> 5) * 512 + ((c0 >> 3) & 3) * 128 + (c0 & 7);
      #pragma unroll
      for (int nt = 0; nt < 4; nt++) {
        int i = ibase + nt * 16 + lane16;
        float s0 = silu_f(acc[mt][nt][0] + bb.x);
        float s1 = silu_f(acc[mt][nt][1] + bb.y);
        float s2 = silu_f(acc[mt][nt][2] + bb.z);
        float s3 = silu_f(acc[mt][nt][3] + bb.w);
        uint2 pq, pk;
        pq.x = pack_bf16(fmaf(s0, g0.x, e0.x), fmaf(s1, g0.y, e0.y));
        pq.y = pack_bf16(fmaf(s2, g0.z, e0.z), fmaf(s3, g0.w, e0.w));
        pk.x = pack_bf16(fmaf(s0, g1.x, e1.x), fmaf(s1, g1.y, e1.y));
        pk.y = pack_bf16(fmaf(s2, g1.z, e1.z), fmaf(s3, g1.w, e1.w));
        size_t off = (size_t)(i >> 4) * 4 * 512 + (size_t)(i & 15) * 8 + coff;
        *(uint2*)(qb + off) = pq;
        *(uint2*)(kb + off) = pk;
      }
    }
  } else {
    int b = by >> 4;                               // batch (by*128 / 2048)
    uint16_t* vt = vT + (size_t)b * DV * S_;
    #pragma unroll
    for (int nt = 0; nt < 4; nt++) {
      int n = (bx - 1) * 128 + wcol + nt * 16 + lane16;   // 0..1023
      float bb = bv[n];
      #pragma unroll
      for (int mt = 0; mt < 4; mt++) {
        int j0l = (by & 15) * 128 + wrow + mt * 16 + quad * 4; // local seq
        uint16_t v0 = f32_to_bf16(silu_f(acc[mt][nt][0] + bb));
        uint16_t v1 = f32_to_bf16(silu_f(acc[mt][nt][1] + bb));
        uint16_t v2 = f32_to_bf16(silu_f(acc[mt][nt][2] + bb));
        uint16_t v3 = f32_to_bf16(silu_f(acc[mt][nt][3] + bb));
        size_t off = (size_t)((n >> 4) * 64 + (j0l >> 5)) * 512 +
                     ((j0l >> 3) & 3) * 128 + (n & 15) * 8 + (j0l & 7);
        uint2 pk;
        pk.x = (uint32_t)v0 | ((uint32_t)v1 << 16);
        pk.y = (uint32_t)v2 | ((uint32_t)v3 << 16);
        *(uint2*)(vt + off) = pk;
      }
    }
  }
}

// attn = laplacian(q@k^T/S + bias[i-j]) causal, TILED bf16 per batch.
// 64x64 tile per 128-thread block (2 waves); exact causal triangle grid.
// SWAPPED: A = kb rows (j), B = qb rows (i).
__global__ __launch_bounds__(128, 4) void k_gemm_sim(
    const uint16_t* __restrict__ qb, const uint16_t* __restrict__ kb,
    const float* __restrict__ bias_n, uint16_t* __restrict__ attn)
{
  int b = blockIdx.x;                    // 0..527 triangular tile index
  int bt = blockIdx.y;                   // batch
  int it = (int)((sqrtf(8.0f * (float)b + 1.0f) - 1.0f) * 0.5f);
  while ((it + 1) * (it + 2) / 2 <= b) ++it;
  while (it * (it + 1) / 2 > b) --it;
  int jt = b - it * (it + 1) / 2;        // 0..it

  int lane = threadIdx.x & 63;
  int wave = threadIdx.x >> 6;           // 0..1 (i-halves of the 64-row tile)
  int lane16 = lane & 15;
  int quad = lane >> 4;

  f32x4 acc[4][2];
  wave_gemm_t<4,2,2>(kb, 4, bt * 128 + jt * 4,
                     qb, 4, bt * 128 + it * 4 + wave * 2,
                     4, acc);

  uint16_t* ab = attn + (size_t)bt * S_ * S_;
  int ibase = it * 64 + wave * 32;
  int jbase = jt * 64;
  #pragma unroll
  for (int nt = 0; nt < 2; nt++) {
    int i = ibase + nt * 16 + lane16;
    size_t irow = (size_t)(i >> 4) * 64 * 512 + (size_t)(i & 15) * 8;
    #pragma unroll
    for (int mt = 0; mt < 4; mt++) {
      int j0 = jbase + mt * 16 + quad * 4;
      float v[4];
      #pragma unroll
      for (int r = 0; r < 4; r++) {
        int j = j0 + r;
        float aval = 0.0f;
        if (j <= i) {
          float sim = acc[mt][nt][r] * (1.0f / 2048.0f) + bias_n[i - j];
          aval = laplacian_attn(sim);
        }
        v[r] = aval;
      }
      uint2 pk;
      pk.x = pack_bf16(v[0], v[1]);
      pk.y = pack_bf16(v[2], v[3]);
      size_t off = irow + (size_t)(j0 >> 5) * 512 + ((j0 >> 3) & 3) * 128 +
                   (j0 & 7);
      *(uint2*)(ab + off) = pk;
    }
  }
}

// out = attn @ v, fp32 out, LDS-staged.  1-D grid 512: XCD c serves ONE bt
// (c>>1); nx=(c&1)*4+(m&3); it=15-(m>>2) (LPT desc). SWAPPED operands:
// A=vT (n rows, staged sA), B=attn (i rows, staged sB) -> float4 stores.
// Wave w: fa rbu=(w&1)*4+mt, fb rbu=(w>>1)*4+nt.
__global__ __launch_bounds__(256, 3) void k_gemm_out(
    const uint16_t* __restrict__ attn, const uint16_t* __restrict__ vT,
    float* __restrict__ out)
{
  int L = blockIdx.x;                    // 0..511
  int c = L & 7, m = L >> 3;             // c: XCD residue, m: 0..63
  int bt = c >> 1;                       // one batch per XCD pair-residue
  int nx = (c & 1) * 4 + (m & 3);        // 0..7
  int it = 15 - (m >> 2);                // descending -> LPT
  int nkb = 4 * it + 4;                  // causal K bound (k-blocks, even)
  WAVE_PREAMBLE

  __shared__ uint16_t sA[8 * 2 * 512];
  __shared__ uint16_t sB[8 * 2 * 512];

  const uint16_t* Ab = vT + (size_t)bt * DV * S_ + (size_t)nx * 8 * 64 * 512;
  const uint16_t* Bb = attn + (size_t)bt * S_ * S_ + (size_t)it * 8 * 64 * 512;

  const uint16_t* gp = (wave >> 1) ? Bb : Ab;
  uint16_t*       sp = (wave >> 1) ? sB : sA;
  int rb0 = (wave & 1) * 4;

  f32x4 acc[4][4];
  #pragma unroll
  for (int mt = 0; mt < 4; mt++)
    #pragma unroll
    for (int nt = 0; nt < 4; nt++) {
      f32x4 z = {0.0f, 0.0f, 0.0f, 0.0f};
      acc[mt][nt] = z;
    }

  for (int kbi = 0; kbi < nkb; kbi += 2) {
    #pragma unroll
    for (int uu = 0; uu < 8; uu++) {
      int rbu = rb0 + (uu >> 1), kk = uu & 1;
      gload16(gp + ((size_t)rbu * 64 + kbi + kk) * 512 + lane * 8,
              sp + (rbu * 2 + kk) * 512);
    }
    __syncthreads();
    #pragma unroll
    for (int kk = 0; kk < 2; kk++) {
      short8 fa[4], fb[4];
      #pragma unroll
      for (int mt = 0; mt < 4; mt++)
        fa[mt] = *(const short8*)(sA + (((wave & 1) * 4 + mt) * 2 + kk) * 512 + lane * 8);
      #pragma unroll
      for (int nt = 0; nt < 4; nt++)
        fb[nt] = *(const short8*)(sB + (((wave >> 1) * 4 + nt) * 2 + kk) * 512 + lane * 8);
      #pragma unroll
      for (int mt = 0; mt < 4; mt++)
        #pragma unroll
        for (int nt = 0; nt < 4; nt++)
          acc[mt][nt] = __builtin_amdgcn_mfma_f32_16x16x32_bf16(
              fa[mt], fb[nt], acc[mt][nt], 0, 0, 0);
    }
    __syncthreads();
  }

  // acc[mt][nt][r]: n = nx*128 + wcol + mt*16 + quad*4 + r
  //                 i = it*128 + wrow + nt*16 + lane16
  float* ob = out + ((size_t)bt * S_ + it * 128 + wrow) * DV + nx * 128 + wcol;
  #pragma unroll
  for (int nt = 0; nt < 4; nt++) {
    int i = nt * 16 + lane16;
    #pragma unroll
    for (int mt = 0; mt < 4; mt++) {
      int n = mt * 16 + quad * 4;
      *(float4*)(ob + (size_t)i * DV + n) = *(float4*)&acc[mt][nt];
    }
  }
}

// ---------------------------------------------------------------------------

extern "C" void kernel_launch(void* const* d_in, const int* in_sizes, int n_in,
                              void* d_out, int out_size, void* d_ws, size_t ws_size,
                              hipStream_t stream)
{
  const float* x     = (const float*)d_in[0];
  const float* wqk   = (const float*)d_in[1];
  const float* bqk   = (const float*)d_in[2];
  const float* gamma = (const float*)d_in[3];
  const float* beta  = (const float*)d_in[4];
  const float* wv    = (const float*)d_in[5];
  const float* bv    = (const float*)d_in[6];
  const float* rel   = (const float*)d_in[7];
  float* out = (float*)d_out;

  char* ws = (char*)d_ws;
  size_t off = 0;
  uint16_t* xb     = (uint16_t*)(ws + off); off += (size_t)B_ * S_ * DIM_ * 2;  // 16 MB
  uint16_t* wT     = (uint16_t*)(ws + off); off += (size_t)NQV * DIM_ * 2;      // 2.25 MB
  uint16_t* qb     = (uint16_t*)(ws + off); off += (size_t)B_ * S_ * DQK * 2;   // 2 MB
  uint16_t* kb     = (uint16_t*)(ws + off); off += (size_t)B_ * S_ * DQK * 2;   // 2 MB
  uint16_t* vT     = (uint16_t*)(ws + off); off += (size_t)B_ * DV * S_ * 2;    // 16 MB
  uint16_t* attn   = (uint16_t*)(ws + off); off += (size_t)B_ * S_ * S_ * 2;    // 32 MB
  float*    bias_n = (float*)(ws + off);    off += (size_t)S_ * 4;              // 8 KB

  k_prep<<<dim3(4673), dim3(256), 0, stream>>>(x, wqk, wv, rel, xb, wT, bias_n);

  k_gemm_qkv<<<dim3(576), dim3(256), 0, stream>>>(
      xb, wT, bqk, gamma, beta, bv, qb, kb, vT);
  k_gemm_sim<<<dim3(528, B_), dim3(128), 0, stream>>>(
      qb, kb, bias_n, attn);
  k_gemm_out<<<dim3(512), dim3(256), 0, stream>>>(
      attn, vT, out);
}